// Round 7
// baseline (357.425 us; speedup 1.0000x reference)
//
#include <hip/hip_runtime.h>
#include <hip/hip_bf16.h>
#include <cmath>

#define LNEPS 1e-5f

typedef __attribute__((ext_vector_type(8))) short short8v;
typedef __attribute__((ext_vector_type(4))) float f32x4;

__device__ __forceinline__ unsigned short f2bf(float f){
  unsigned u = __float_as_uint(f);
  u += 0x7fffu + ((u >> 16) & 1u);
  return (unsigned short)(u >> 16);
}
// tanh-form GELU (max |diff| vs exact erf-GELU ~3e-4 -- invisible in bf16 h).
__device__ __forceinline__ float gelu_f(float x){
  const float y = 0.7978845608028654f * x * (1.f + 0.044715f * x * x);
  const float e = __expf(-2.f * fabsf(y));
  const float t = __builtin_copysignf((1.f - e) / (1.f + e), y);
  return 0.5f * x * (1.f + t);
}

// Device-guarded MFMA wrapper: host pass must never see target builtins.
__device__ __forceinline__ f32x4 mfma32(short8v a, short8v b, f32x4 c){
#ifdef __HIP_DEVICE_COMPILE__
  return __builtin_amdgcn_mfma_f32_16x16x32_bf16(a, b, c, 0, 0, 0);
#else
  return c;
#endif
}

// Stage 128 rows x 128 bf16 from global [r][ldg] into XOR-swizzled LDS (row stride 256B).
__device__ __forceinline__ void stage128(const unsigned short* g, int ldg, short* lds){
  const int t = threadIdx.x;
  #pragma unroll
  for (int it = 0; it < 8; ++it) {
    const int flat = it * 256 + t;
    const int r = flat >> 4, c = flat & 15;
    const uint4 v = *(const uint4*)(g + (size_t)r * ldg + c * 8);
    *(uint4*)((char*)lds + r * 256 + ((c ^ (r & 7)) << 4)) = v;
  }
}
// Swizzled 16B fragment read: row-major [row][128 bf16] (256B rows).
__device__ __forceinline__ short8v frag_ld(const short* lds, int row, int chunk){
  return *(const short8v*)((const char*)lds + row * 256 + ((chunk ^ (row & 7)) << 4));
}
// Swizzled 16B fragment read: row-major [row][64 bf16] (128B rows).
__device__ __forceinline__ short8v frag_ld64(const short* lds, int row, int chunk){
  return *(const short8v*)((const char*)lds + row * 128 + ((chunk ^ (row & 7)) << 4));
}

// ---------------- K0: weights f32 -> bf16 ----------------
__global__ __launch_bounds__(256) void k0_cvt(
    const float* __restrict__ qkvw, const float* __restrict__ pw,
    const float* __restrict__ w1, const float* __restrict__ w2,
    unsigned short* __restrict__ dst)
{
  const int i = (blockIdx.x * 256 + threadIdx.x) * 4;
  const float* src; int off;
  if (i < 49152)       { src = qkvw; off = i; }
  else if (i < 65536)  { src = pw;   off = i - 49152; }
  else if (i < 131072) { src = w1;   off = i - 65536; }
  else                 { src = w2;   off = i - 131072; }
  const float4 v = *(const float4*)(src + off);
  ushort4 o = { f2bf(v.x), f2bf(v.y), f2bf(v.z), f2bf(v.w) };
  *(ushort4*)(dst + i) = o;
}

// ---------------- K1: LN1 + shift + window partition -> win bf16 [131072][128] ----------------
__global__ __launch_bounds__(256) void k1_ln1_window(
    const float* __restrict__ x, const float* __restrict__ gw, const float* __restrict__ gb,
    unsigned short* __restrict__ win)
{
  const int lane = threadIdx.x & 63;
  const int wave = threadIdx.x >> 6;
  const int row  = blockIdx.x * 4 + wave;
  const int wid = row >> 6, n = row & 63;
  const int b = wid >> 10, rem = wid & 1023;
  const int wh = rem >> 5, wwi = rem & 31;
  const int i = n >> 3, j = n & 7;
  const int sh = (wh * 8 + i + 4) & 255;
  const int sw = (wwi * 8 + j + 4) & 255;
  const float2 v = *(const float2*)(x + (((size_t)b << 16) + sh * 256 + sw) * 128 + lane * 2);
  float s = v.x + v.y, ss = v.x * v.x + v.y * v.y;
  #pragma unroll
  for (int o = 1; o < 64; o <<= 1) { s += __shfl_xor(s, o); ss += __shfl_xor(ss, o); }
  const float mean = s * 0.0078125f;
  const float rstd = rsqrtf(ss * 0.0078125f - mean * mean + LNEPS);
  const float2 w2 = *(const float2*)(gw + lane * 2);
  const float2 b2 = *(const float2*)(gb + lane * 2);
  const unsigned lo = f2bf((v.x - mean) * rstd * w2.x + b2.x);
  const unsigned hi = f2bf((v.y - mean) * rstd * w2.y + b2.y);
  *(unsigned*)(win + (size_t)row * 128 + lane * 2) = lo | (hi << 16);
}

// ---------------- K2: qkv MFMA GEMM -> qk bf16 [131072][256] + vt bf16 [16384][16][64] ----------------
__global__ __launch_bounds__(256, 2) void k2_qkv(
    const unsigned short* __restrict__ A,
    const unsigned short* __restrict__ Wb,
    const float* __restrict__ bias,
    unsigned short* __restrict__ qk,
    unsigned short* __restrict__ vt)
{
  __shared__ __align__(16) short At[128 * 128];
  __shared__ __align__(16) short Bt[128 * 128];
  const int t = threadIdx.x;
  const int row0 = blockIdx.x * 128, n0 = blockIdx.y * 128;
  stage128(Wb + (size_t)n0 * 128, 128, At);
  stage128(A + (size_t)row0 * 128, 128, Bt);
  __syncthreads();
  const int l = t & 63, w = t >> 6, w0 = w & 1, w1 = w >> 1;
  const int g = l >> 4, rl = l & 15;
  const f32x4 z = {0.f, 0.f, 0.f, 0.f};
  f32x4 acc[4][4];
  #pragma unroll
  for (int i = 0; i < 4; ++i)
    #pragma unroll
    for (int j = 0; j < 4; ++j) acc[i][j] = z;
  #pragma unroll
  for (int kk = 0; kk < 4; ++kk) {
    short8v a[4], b[4];
    #pragma unroll
    for (int i = 0; i < 4; ++i) a[i] = frag_ld(At, w0 * 64 + i * 16 + rl, kk * 4 + g);
    #pragma unroll
    for (int j = 0; j < 4; ++j) b[j] = frag_ld(Bt, w1 * 64 + j * 16 + rl, kk * 4 + g);
    #pragma unroll
    for (int i = 0; i < 4; ++i)
      #pragma unroll
      for (int j = 0; j < 4; ++j)
        acc[i][j] = mfma32(a[i], b[j], acc[i][j]);
  }
  if (blockIdx.y < 2) {
    #pragma unroll
    for (int i = 0; i < 4; ++i) {
      const int np = w0 * 64 + i * 16 + 4 * g;
      const float4 bv = *(const float4*)(bias + n0 + np);
      #pragma unroll
      for (int j = 0; j < 4; ++j) {
        const int r = row0 + w1 * 64 + j * 16 + rl;
        ushort4 o = { f2bf(acc[i][j][0] + bv.x), f2bf(acc[i][j][1] + bv.y),
                      f2bf(acc[i][j][2] + bv.z), f2bf(acc[i][j][3] + bv.w) };
        *(ushort4*)(qk + (size_t)r * 256 + n0 + np) = o;
      }
    }
  } else {
    #pragma unroll
    for (int i = 0; i < 4; ++i) {
      const int np = w0 * 64 + i * 16 + 4 * g;
      const int h = np >> 4, db = np & 15;
      const float4 bv = *(const float4*)(bias + 256 + np);
      const float ba[4] = {bv.x, bv.y, bv.z, bv.w};
      #pragma unroll
      for (int j = 0; j < 4; ++j) {
        const int r = row0 + w1 * 64 + j * 16 + rl;
        const int wn = r >> 6, m = r & 63;
        unsigned short* dst = vt + (((size_t)wn * 8 + h) << 10) + m;
        #pragma unroll
        for (int e = 0; e < 4; ++e)
          dst[(db + e) * 64] = f2bf(acc[i][j][e] + ba[e]);
      }
    }
  }
}

// ---------------- K3: MFMA window attention (16x16x32 only), one wave per (window, head) ----------------
__global__ __launch_bounds__(256, 2) void k3_attn(
    const unsigned short* __restrict__ qk,
    const unsigned short* __restrict__ vt,
    const float* __restrict__ table,
    unsigned short* __restrict__ attn)
{
  __shared__ float Tb[1800];
  __shared__ __align__(16) unsigned short Pl[4][4096];   // per-wave P [r][m] bf16, XOR-swizzled
  const int t = threadIdx.x;
  for (int i = t; i < 1800; i += 256) Tb[i] = table[i];
  __syncthreads();
  const int l = t & 63, w = t >> 6;
  const int id = blockIdx.x * 4 + w;
  const int win = id >> 3, h = id & 7;
  const int g = l >> 4, rl = l & 15;
  // ---- QK^T via 16x16x32, K zero-padded (head_dim = 16 -> lanes g>=2 hold zeros) ----
  const unsigned short* qbase = qk + (size_t)win * 64 * 256 + h * 16;
  const short8v zz = {0,0,0,0,0,0,0,0};
  short8v qf[4], kf[4];
  if (g < 2) {
    #pragma unroll
    for (int rf = 0; rf < 4; ++rf)
      qf[rf] = *(const short8v*)(qbase + (size_t)(rf * 16 + rl) * 256 + g * 8);
    #pragma unroll
    for (int mf = 0; mf < 4; ++mf)
      kf[mf] = *(const short8v*)(qbase + 128 + (size_t)(mf * 16 + rl) * 256 + g * 8);
  } else {
    #pragma unroll
    for (int i = 0; i < 4; ++i) { qf[i] = zz; kf[i] = zz; }
  }
  const f32x4 z = {0.f, 0.f, 0.f, 0.f};
  f32x4 s[4][4];
  #pragma unroll
  for (int mf = 0; mf < 4; ++mf)
    #pragma unroll
    for (int rf = 0; rf < 4; ++rf)
      s[mf][rf] = mfma32(kf[mf], qf[rf], z);   // S^T: m = mf*16+4g+e, r = rf*16+rl
  // ---- bias + softmax (m runs over lanes sharing rl: xor 16/32) ----
  float sum[4];
  #pragma unroll
  for (int rf = 0; rf < 4; ++rf) {
    const int r = rf * 16 + rl, i1 = r >> 3, j1 = r & 7;
    float mx = -1e30f;
    #pragma unroll
    for (int mf = 0; mf < 4; ++mf)
      #pragma unroll
      for (int e = 0; e < 4; ++e) {
        const int m = mf * 16 + g * 4 + e;
        const int i2 = m >> 3, j2 = m & 7;
        const float v = s[mf][rf][e] * 0.25f + Tb[((i1 - i2 + 7) * 15 + (j1 - j2 + 7)) * 8 + h];
        s[mf][rf][e] = v;
        mx = fmaxf(mx, v);
      }
    mx = fmaxf(mx, __shfl_xor(mx, 16));
    mx = fmaxf(mx, __shfl_xor(mx, 32));
    float sm = 0.f;
    #pragma unroll
    for (int mf = 0; mf < 4; ++mf)
      #pragma unroll
      for (int e = 0; e < 4; ++e) {
        const float ev = __expf(s[mf][rf][e] - mx);
        s[mf][rf][e] = ev;
        sm += ev;
      }
    sm += __shfl_xor(sm, 16);
    sm += __shfl_xor(sm, 32);
    sum[rf] = sm;
  }
  // ---- pack P to bf16 and round-trip through per-wave LDS (intra-wave, no barrier) ----
  char* Pw = (char*)&Pl[w][0];
  #pragma unroll
  for (int rf = 0; rf < 4; ++rf) {
    const int r = rf * 16 + rl;
    const int swz = (r & 7) << 4;
    #pragma unroll
    for (int mf = 0; mf < 4; ++mf) {
      uint2 u;
      u.x = (unsigned)f2bf(s[mf][rf][0]) | ((unsigned)f2bf(s[mf][rf][1]) << 16);
      u.y = (unsigned)f2bf(s[mf][rf][2]) | ((unsigned)f2bf(s[mf][rf][3]) << 16);
      *(uint2*)(Pw + ((r * 128 + mf * 32 + g * 8) ^ swz)) = u;
    }
  }
  // ---- PV: O^T = V^T (A) x P^T (B), K = 32, 2 K-blocks ----
  const unsigned short* vb = vt + (((size_t)win * 8 + h) << 10) + rl * 64 + g * 8;
  f32x4 o[4];
  #pragma unroll
  for (int rf = 0; rf < 4; ++rf) o[rf] = z;
  #pragma unroll
  for (int c = 0; c < 2; ++c) {
    const short8v va = *(const short8v*)(vb + c * 32);
    #pragma unroll
    for (int rf = 0; rf < 4; ++rf) {
      const int r = rf * 16 + rl;
      const short8v pb = *(const short8v*)(Pw + ((r * 128 + c * 64 + g * 16) ^ ((r & 7) << 4)));
      o[rf] = mfma32(va, pb, o[rf]);
    }
  }
  #pragma unroll
  for (int rf = 0; rf < 4; ++rf) {
    const float inv = 1.f / sum[rf];
    const int r = rf * 16 + rl;
    ushort4 ov = { f2bf(o[rf][0] * inv), f2bf(o[rf][1] * inv),
                   f2bf(o[rf][2] * inv), f2bf(o[rf][3] * inv) };
    *(ushort4*)(attn + ((size_t)win * 64 + r) * 128 + h * 16 + g * 4) = ov;
  }
}

// ---------------- K4: proj MFMA + window reverse + unshift + residual -> d_out (f32) ----------------
__global__ __launch_bounds__(256, 2) void k4_proj(
    const unsigned short* __restrict__ A,
    const unsigned short* __restrict__ Wb,
    const float* __restrict__ bias,
    const float* __restrict__ xin,
    float* __restrict__ out)
{
  __shared__ __align__(16) short At[128 * 128];
  __shared__ __align__(16) short Bt[128 * 128];
  const int t = threadIdx.x;
  const int row0 = blockIdx.x * 128;
  stage128(Wb, 128, At);
  stage128(A + (size_t)row0 * 128, 128, Bt);
  __syncthreads();
  const int l = t & 63, w = t >> 6, w0 = w & 1, w1 = w >> 1;
  const int g = l >> 4, rl = l & 15;
  const f32x4 z = {0.f, 0.f, 0.f, 0.f};
  f32x4 acc[4][4];
  #pragma unroll
  for (int i = 0; i < 4; ++i)
    #pragma unroll
    for (int j = 0; j < 4; ++j) acc[i][j] = z;
  #pragma unroll
  for (int kk = 0; kk < 4; ++kk) {
    short8v a[4], b[4];
    #pragma unroll
    for (int i = 0; i < 4; ++i) a[i] = frag_ld(At, w0 * 64 + i * 16 + rl, kk * 4 + g);
    #pragma unroll
    for (int j = 0; j < 4; ++j) b[j] = frag_ld(Bt, w1 * 64 + j * 16 + rl, kk * 4 + g);
    #pragma unroll
    for (int i = 0; i < 4; ++i)
      #pragma unroll
      for (int j = 0; j < 4; ++j)
        acc[i][j] = mfma32(a[i], b[j], acc[i][j]);
  }
  #pragma unroll
  for (int i = 0; i < 4; ++i) {
    const int c = w0 * 64 + i * 16 + 4 * g;
    const float4 bv = *(const float4*)(bias + c);
    #pragma unroll
    for (int j = 0; j < 4; ++j) {
      const int r = row0 + w1 * 64 + j * 16 + rl;
      const int wn = r >> 6, n = r & 63;
      const int b_ = wn >> 10, rem = wn & 1023;
      const int wh = rem >> 5, ww = rem & 31;
      const int si = n >> 3, sj = n & 7;
      const int hd = (wh * 8 + si + 4) & 255;
      const int wd = (ww * 8 + sj + 4) & 255;
      const size_t off = (((size_t)b_ << 16) + hd * 256 + wd) * 128 + c;
      const float4 xv = *(const float4*)(xin + off);
      float4 o = { xv.x + acc[i][j][0] + bv.x, xv.y + acc[i][j][1] + bv.y,
                   xv.z + acc[i][j][2] + bv.z, xv.w + acc[i][j][3] + bv.w };
      *(float4*)(out + off) = o;
    }
  }
}

// ---------------- K5: fused LN2 + fc1 + GELU + fc2 + residual ----------------
// 40 KB LDS -> 4 blocks/CU. X-frags live in registers (Xt space reused as W1 tile).
// 8 phases x 64 fc1-cols; 2 barriers/phase; {fc1, GELU, fc2} barrier-free (wave-local h).
// T14: next phase's W1+W2 slices prefetched into 8 uint4 regs one phase ahead.
__global__ __launch_bounds__(256, 4) void k5_mlp(
    const float* x2,
    const float* __restrict__ gw, const float* __restrict__ gb,
    const unsigned short* __restrict__ w1b, const float* __restrict__ b1,
    const unsigned short* __restrict__ w2b, const float* __restrict__ b2,
    float* out)
{
  __shared__ __align__(16) short SA[64 * 128];           // 16 KB: ln2(x2) tile, then W1 slice
  __shared__ __align__(16) short SB[128 * 64];           // 16 KB: W2 slice [outcol][64 k]
  __shared__ __align__(16) unsigned short SH[4][1024];   // 8 KB: per-wave h (16 rows x 64 cols)
  const int t = threadIdx.x;
  const size_t row0 = (size_t)blockIdx.x * 64;
  const int wv = t >> 6, l = t & 63;
  const int g = l >> 4, rl = l & 15;
  const int wrow = wv * 16 + rl;
  const int w1r = t >> 2, w1c = (t & 3) * 4;   // W1 slice: 64 rows x 16 chunks, 4 uint4/thread
  const int w2r = t >> 1, w2c = (t & 1) * 4;   // W2 slice: 128 rows x 8 chunks, 4 uint4/thread

  // T14: issue W1[0], W2[0] loads -- latency hides under LN.
  uint4 wr1[4], wr2[4];
  #pragma unroll
  for (int q = 0; q < 4; ++q) {
    wr1[q] = *(const uint4*)(w1b + (size_t)w1r * 128 + (w1c + q) * 8);
    wr2[q] = *(const uint4*)(w2b + (size_t)w2r * 512 + (w2c + q) * 8);
  }

  {
    // LN2: 4 threads per row over 64 rows -> SA (swizzled bf16).
    const int rr = t >> 2, qq = t & 3;
    const float* src = x2 + (row0 + rr) * 128 + qq * 32;
    float v[32]; float s = 0.f, ss = 0.f;
    #pragma unroll
    for (int q = 0; q < 8; ++q) {
      const float4 a4 = *(const float4*)(src + q * 4);
      v[q*4+0] = a4.x; v[q*4+1] = a4.y; v[q*4+2] = a4.z; v[q*4+3] = a4.w;
      s  += a4.x + a4.y + a4.z + a4.w;
      ss += a4.x*a4.x + a4.y*a4.y + a4.z*a4.z + a4.w*a4.w;
    }
    s += __shfl_xor(s, 1); ss += __shfl_xor(ss, 1);
    s += __shfl_xor(s, 2); ss += __shfl_xor(ss, 2);
    const float mean = s * 0.0078125f;
    const float rstd = rsqrtf(ss * 0.0078125f - mean * mean + LNEPS);
    #pragma unroll
    for (int cc = 0; cc < 4; ++cc) {
      const int col = qq * 32 + cc * 8;
      const float4 g0 = *(const float4*)(gw + col), g1 = *(const float4*)(gw + col + 4);
      const float4 c0 = *(const float4*)(gb + col), c1 = *(const float4*)(gb + col + 4);
      uint4 pk;
      pk.x = (unsigned)f2bf((v[cc*8+0]-mean)*rstd*g0.x + c0.x)
           | ((unsigned)f2bf((v[cc*8+1]-mean)*rstd*g0.y + c0.y) << 16);
      pk.y = (unsigned)f2bf((v[cc*8+2]-mean)*rstd*g0.z + c0.z)
           | ((unsigned)f2bf((v[cc*8+3]-mean)*rstd*g0.w + c0.w) << 16);
      pk.z = (unsigned)f2bf((v[cc*8+4]-mean)*rstd*g1.x + c1.x)
           | ((unsigned)f2bf((v[cc*8+5]-mean)*rstd*g1.y + c1.y) << 16);
      pk.w = (unsigned)f2bf((v[cc*8+6]-mean)*rstd*g1.z + c1.z)
           | ((unsigned)f2bf((v[cc*8+7]-mean)*rstd*g1.w + c1.w) << 16);
      const int chunk = qq * 4 + cc;
      *(uint4*)((char*)SA + rr * 256 + ((chunk ^ (rr & 7)) << 4)) = pk;
    }
  }
  __syncthreads();                 // SA = ln2(x2) visible
  // X B-frags -> registers (wave-local rows), freeing SA for W1.
  short8v bf[4];
  #pragma unroll
  for (int kk = 0; kk < 4; ++kk) bf[kk] = frag_ld(SA, wrow, kk * 4 + g);
  __syncthreads();                 // all x-frag reads done -> SA reusable
  #pragma unroll
  for (int q = 0; q < 4; ++q) {
    *(uint4*)((char*)SA + w1r * 256 + (((w1c + q) ^ (w1r & 7)) << 4)) = wr1[q];
    *(uint4*)((char*)SB + w2r * 128 + (((w2c + q) ^ (w2r & 7)) << 4)) = wr2[q];
  }
  #pragma unroll
  for (int q = 0; q < 4; ++q) {    // prefetch phase 1
    wr1[q] = *(const uint4*)(w1b + (size_t)(64 * 128) + (size_t)w1r * 128 + (w1c + q) * 8);
    wr2[q] = *(const uint4*)(w2b + (size_t)w2r * 512 + 64 + (w2c + q) * 8);
  }
  __syncthreads();                 // W[0] visible

  const f32x4 z = {0.f, 0.f, 0.f, 0.f};
  f32x4 oacc[8];
  #pragma unroll
  for (int i = 0; i < 8; ++i) oacc[i] = z;
  char* Hw = (char*)&SH[wv][0];
  const int hswz = (rl & 7) << 4;

  for (int s = 0; s < 8; ++s) {
    // ---- fc1: h[64 cols][16 own rows] ----
    f32x4 hacc[4];
    #pragma unroll
    for (int i = 0; i < 4; ++i) hacc[i] = z;
    #pragma unroll
    for (int kk = 0; kk < 4; ++kk)
      #pragma unroll
      for (int i = 0; i < 4; ++i)
        hacc[i] = mfma32(frag_ld(SA, i * 16 + rl, kk * 4 + g), bf[kk], hacc[i]);
    // ---- GELU half 0 (cols 0..31) -> SH; fc2 kk=0 ----
    #pragma unroll
    for (int i = 0; i < 2; ++i) {
      const float4 b1v = *(const float4*)(b1 + s * 64 + i * 16 + 4 * g);
      uint2 u;
      u.x = (unsigned)f2bf(gelu_f(hacc[i][0] + b1v.x))
          | ((unsigned)f2bf(gelu_f(hacc[i][1] + b1v.y)) << 16);
      u.y = (unsigned)f2bf(gelu_f(hacc[i][2] + b1v.z))
          | ((unsigned)f2bf(gelu_f(hacc[i][3] + b1v.w)) << 16);
      *(uint2*)(Hw + rl * 128 + ((i * 32 + g * 8) ^ hswz)) = u;
    }
    {
      const short8v hb = *(const short8v*)(Hw + rl * 128 + ((g * 16) ^ hswz));
      #pragma unroll
      for (int i = 0; i < 8; ++i)
        oacc[i] = mfma32(frag_ld64(SB, i * 16 + rl, g), hb, oacc[i]);
    }
    // ---- GELU half 1 (cols 32..63) -> SH; fc2 kk=1 ----
    #pragma unroll
    for (int i = 2; i < 4; ++i) {
      const float4 b1v = *(const float4*)(b1 + s * 64 + i * 16 + 4 * g);
      uint2 u;
      u.x = (unsigned)f2bf(gelu_f(hacc[i][0] + b1v.x))
          | ((unsigned)f2bf(gelu_f(hacc[i][1] + b1v.y)) << 16);
      u.y = (unsigned)f2bf(gelu_f(hacc[i][2] + b1v.z))
          | ((unsigned)f2bf(gelu_f(hacc[i][3] + b1v.w)) << 16);
      *(uint2*)(Hw + rl * 128 + ((i * 32 + g * 8) ^ hswz)) = u;
    }
    {
      const short8v hb = *(const short8v*)(Hw + rl * 128 + ((64 + g * 16) ^ hswz));
      #pragma unroll
      for (int i = 0; i < 8; ++i)
        oacc[i] = mfma32(frag_ld64(SB, i * 16 + rl, 4 + g), hb, oacc[i]);
    }
    // ---- stage next phase ----
    if (s < 7) {
      __syncthreads();             // everyone done reading SA/SB[s]
      #pragma unroll
      for (int q = 0; q < 4; ++q) {
        *(uint4*)((char*)SA + w1r * 256 + (((w1c + q) ^ (w1r & 7)) << 4)) = wr1[q];
        *(uint4*)((char*)SB + w2r * 128 + (((w2c + q) ^ (w2r & 7)) << 4)) = wr2[q];
      }
      if (s < 6) {
        #pragma unroll
        for (int q = 0; q < 4; ++q) {
          wr1[q] = *(const uint4*)(w1b + (size_t)(s + 2) * 8192 + (size_t)w1r * 128 + (w1c + q) * 8);
          wr2[q] = *(const uint4*)(w2b + (size_t)w2r * 512 + (s + 2) * 64 + (w2c + q) * 8);
        }
      }
      __syncthreads();             // W[s+1] visible
    }
  }

  // ---- epilogue: out = x2 + oacc + b2 ----
  const size_t orow = row0 + wrow;
  #pragma unroll
  for (int i = 0; i < 8; ++i) {
    const int c = i * 16 + 4 * g;
    const float4 bv = *(const float4*)(b2 + c);
    const float4 xv = *(const float4*)(x2 + orow * 128 + c);
    float4 o = { xv.x + oacc[i][0] + bv.x, xv.y + oacc[i][1] + bv.y,
                 xv.z + oacc[i][2] + bv.z, xv.w + oacc[i][3] + bv.w };
    *(float4*)(out + orow * 128 + c) = o;
  }
}

extern "C" void kernel_launch(void* const* d_in, const int* in_sizes, int n_in,
                              void* d_out, int out_size, void* d_ws, size_t ws_size,
                              hipStream_t stream)
{
  const float* x    = (const float*)d_in[0];
  const float* n1w  = (const float*)d_in[1];
  const float* n1b  = (const float*)d_in[2];
  const float* qkvw = (const float*)d_in[3];
  const float* qkvB = (const float*)d_in[4];
  const float* relb = (const float*)d_in[5];
  const float* pw   = (const float*)d_in[6];
  const float* pb   = (const float*)d_in[7];
  const float* n2w  = (const float*)d_in[8];
  const float* n2b  = (const float*)d_in[9];
  const float* w1   = (const float*)d_in[10];
  const float* b1   = (const float*)d_in[11];
  const float* w2   = (const float*)d_in[12];
  const float* b2   = (const float*)d_in[13];
  float* out = (float*)d_out;

  unsigned short* winb = (unsigned short*)d_ws;        // 16,777,216 el (LN1 out; reused as attn out)
  unsigned short* qkb  = winb + 16777216;              // 33,554,432 el  Q|K interleaved [row][256]
  unsigned short* vtb  = qkb + 33554432;               // 16,777,216 el  V^T per (win,head): [16][64]
  unsigned short* wb   = vtb + 16777216;               // 196,608 el  bf16 weights
  unsigned short* qkvw_b = wb;
  unsigned short* pw_b   = wb + 49152;
  unsigned short* w1_b   = wb + 65536;
  unsigned short* w2_b   = wb + 131072;

  k0_cvt<<<192, 256, 0, stream>>>(qkvw, pw, w1, w2, wb);
  k1_ln1_window<<<32768, 256, 0, stream>>>(x, n1w, n1b, winb);
  k2_qkv<<<dim3(1024, 3), 256, 0, stream>>>(winb, qkvw_b, qkvB, qkb, vtb);
  k3_attn<<<4096, 256, 0, stream>>>(qkb, vtb, relb, winb);
  k4_proj<<<1024, 256, 0, stream>>>(winb, pw_b, pb, x, out);
  k5_mlp<<<2048, 256, 0, stream>>>(out, n2w, n2b, w1_b, b1, w2_b, b2, out);
}

// Round 8
// 323.220 us; speedup vs baseline: 1.1058x; 1.1058x over previous
//
#include <hip/hip_runtime.h>
#include <hip/hip_bf16.h>
#include <cmath>

#define LNEPS 1e-5f

typedef __attribute__((ext_vector_type(8))) short short8v;
typedef __attribute__((ext_vector_type(4))) float f32x4;

__device__ __forceinline__ unsigned short f2bf(float f){
  unsigned u = __float_as_uint(f);
  u += 0x7fffu + ((u >> 16) & 1u);
  return (unsigned short)(u >> 16);
}
// tanh-form GELU (max |diff| vs exact erf-GELU ~3e-4 -- invisible in bf16 h; validated r6/r7).
__device__ __forceinline__ float gelu_f(float x){
  const float y = 0.7978845608028654f * x * (1.f + 0.044715f * x * x);
  const float e = __expf(-2.f * fabsf(y));
  const float t = __builtin_copysignf((1.f - e) / (1.f + e), y);
  return 0.5f * x * (1.f + t);
}

// Device-guarded MFMA wrapper: host pass must never see target builtins.
__device__ __forceinline__ f32x4 mfma32(short8v a, short8v b, f32x4 c){
#ifdef __HIP_DEVICE_COMPILE__
  return __builtin_amdgcn_mfma_f32_16x16x32_bf16(a, b, c, 0, 0, 0);
#else
  return c;
#endif
}

// Stage 128 rows x 128 bf16 from global [r][ldg] into XOR-swizzled LDS (row stride 256B).
__device__ __forceinline__ void stage128(const unsigned short* g, int ldg, short* lds){
  const int t = threadIdx.x;
  #pragma unroll
  for (int it = 0; it < 8; ++it) {
    const int flat = it * 256 + t;
    const int r = flat >> 4, c = flat & 15;
    const uint4 v = *(const uint4*)(g + (size_t)r * ldg + c * 8);
    *(uint4*)((char*)lds + r * 256 + ((c ^ (r & 7)) << 4)) = v;
  }
}
// Swizzled 16B fragment read: row-major [row][128 bf16] (256B rows).
__device__ __forceinline__ short8v frag_ld(const short* lds, int row, int chunk){
  return *(const short8v*)((const char*)lds + row * 256 + ((chunk ^ (row & 7)) << 4));
}

// ---------------- K0: weights f32 -> bf16 ----------------
__global__ __launch_bounds__(256) void k0_cvt(
    const float* __restrict__ qkvw, const float* __restrict__ pw,
    const float* __restrict__ w1, const float* __restrict__ w2,
    unsigned short* __restrict__ dst)
{
  const int i = (blockIdx.x * 256 + threadIdx.x) * 4;
  const float* src; int off;
  if (i < 49152)       { src = qkvw; off = i; }
  else if (i < 65536)  { src = pw;   off = i - 49152; }
  else if (i < 131072) { src = w1;   off = i - 65536; }
  else                 { src = w2;   off = i - 131072; }
  const float4 v = *(const float4*)(src + off);
  ushort4 o = { f2bf(v.x), f2bf(v.y), f2bf(v.z), f2bf(v.w) };
  *(ushort4*)(dst + i) = o;
}

// ---------------- K1: LN1 + shift + window partition -> win bf16 [131072][128] ----------------
__global__ __launch_bounds__(256) void k1_ln1_window(
    const float* __restrict__ x, const float* __restrict__ gw, const float* __restrict__ gb,
    unsigned short* __restrict__ win)
{
  const int lane = threadIdx.x & 63;
  const int wave = threadIdx.x >> 6;
  const int row  = blockIdx.x * 4 + wave;
  const int wid = row >> 6, n = row & 63;
  const int b = wid >> 10, rem = wid & 1023;
  const int wh = rem >> 5, wwi = rem & 31;
  const int i = n >> 3, j = n & 7;
  const int sh = (wh * 8 + i + 4) & 255;
  const int sw = (wwi * 8 + j + 4) & 255;
  const float2 v = *(const float2*)(x + (((size_t)b << 16) + sh * 256 + sw) * 128 + lane * 2);
  float s = v.x + v.y, ss = v.x * v.x + v.y * v.y;
  #pragma unroll
  for (int o = 1; o < 64; o <<= 1) { s += __shfl_xor(s, o); ss += __shfl_xor(ss, o); }
  const float mean = s * 0.0078125f;
  const float rstd = rsqrtf(ss * 0.0078125f - mean * mean + LNEPS);
  const float2 w2 = *(const float2*)(gw + lane * 2);
  const float2 b2 = *(const float2*)(gb + lane * 2);
  const unsigned lo = f2bf((v.x - mean) * rstd * w2.x + b2.x);
  const unsigned hi = f2bf((v.y - mean) * rstd * w2.y + b2.y);
  *(unsigned*)(win + (size_t)row * 128 + lane * 2) = lo | (hi << 16);
}

// ---------------- K2: qkv MFMA GEMM -> qk bf16 [131072][256] + vt bf16 [16384][16][64] ----------------
__global__ __launch_bounds__(256, 2) void k2_qkv(
    const unsigned short* __restrict__ A,
    const unsigned short* __restrict__ Wb,
    const float* __restrict__ bias,
    unsigned short* __restrict__ qk,
    unsigned short* __restrict__ vt)
{
  __shared__ __align__(16) short At[128 * 128];
  __shared__ __align__(16) short Bt[128 * 128];
  const int t = threadIdx.x;
  const int row0 = blockIdx.x * 128, n0 = blockIdx.y * 128;
  stage128(Wb + (size_t)n0 * 128, 128, At);
  stage128(A + (size_t)row0 * 128, 128, Bt);
  __syncthreads();
  const int l = t & 63, w = t >> 6, w0 = w & 1, w1 = w >> 1;
  const int g = l >> 4, rl = l & 15;
  const f32x4 z = {0.f, 0.f, 0.f, 0.f};
  f32x4 acc[4][4];
  #pragma unroll
  for (int i = 0; i < 4; ++i)
    #pragma unroll
    for (int j = 0; j < 4; ++j) acc[i][j] = z;
  #pragma unroll
  for (int kk = 0; kk < 4; ++kk) {
    short8v a[4], b[4];
    #pragma unroll
    for (int i = 0; i < 4; ++i) a[i] = frag_ld(At, w0 * 64 + i * 16 + rl, kk * 4 + g);
    #pragma unroll
    for (int j = 0; j < 4; ++j) b[j] = frag_ld(Bt, w1 * 64 + j * 16 + rl, kk * 4 + g);
    #pragma unroll
    for (int i = 0; i < 4; ++i)
      #pragma unroll
      for (int j = 0; j < 4; ++j)
        acc[i][j] = mfma32(a[i], b[j], acc[i][j]);
  }
  if (blockIdx.y < 2) {
    #pragma unroll
    for (int i = 0; i < 4; ++i) {
      const int np = w0 * 64 + i * 16 + 4 * g;
      const float4 bv = *(const float4*)(bias + n0 + np);
      #pragma unroll
      for (int j = 0; j < 4; ++j) {
        const int r = row0 + w1 * 64 + j * 16 + rl;
        ushort4 o = { f2bf(acc[i][j][0] + bv.x), f2bf(acc[i][j][1] + bv.y),
                      f2bf(acc[i][j][2] + bv.z), f2bf(acc[i][j][3] + bv.w) };
        *(ushort4*)(qk + (size_t)r * 256 + n0 + np) = o;
      }
    }
  } else {
    #pragma unroll
    for (int i = 0; i < 4; ++i) {
      const int np = w0 * 64 + i * 16 + 4 * g;
      const int h = np >> 4, db = np & 15;
      const float4 bv = *(const float4*)(bias + 256 + np);
      const float ba[4] = {bv.x, bv.y, bv.z, bv.w};
      #pragma unroll
      for (int j = 0; j < 4; ++j) {
        const int r = row0 + w1 * 64 + j * 16 + rl;
        const int wn = r >> 6, m = r & 63;
        unsigned short* dst = vt + (((size_t)wn * 8 + h) << 10) + m;
        #pragma unroll
        for (int e = 0; e < 4; ++e)
          dst[(db + e) * 64] = f2bf(acc[i][j][e] + ba[e]);
      }
    }
  }
}

// ---------------- K3: MFMA window attention (16x16x32 only), one wave per (window, head) ----------------
__global__ __launch_bounds__(256, 2) void k3_attn(
    const unsigned short* __restrict__ qk,
    const unsigned short* __restrict__ vt,
    const float* __restrict__ table,
    unsigned short* __restrict__ attn)
{
  __shared__ float Tb[1800];
  __shared__ __align__(16) unsigned short Pl[4][4096];   // per-wave P [r][m] bf16, XOR-swizzled
  const int t = threadIdx.x;
  for (int i = t; i < 1800; i += 256) Tb[i] = table[i];
  __syncthreads();
  const int l = t & 63, w = t >> 6;
  const int id = blockIdx.x * 4 + w;
  const int win = id >> 3, h = id & 7;
  const int g = l >> 4, rl = l & 15;
  // ---- QK^T via 16x16x32, K zero-padded (head_dim = 16 -> lanes g>=2 hold zeros) ----
  const unsigned short* qbase = qk + (size_t)win * 64 * 256 + h * 16;
  const short8v zz = {0,0,0,0,0,0,0,0};
  short8v qf[4], kf[4];
  if (g < 2) {
    #pragma unroll
    for (int rf = 0; rf < 4; ++rf)
      qf[rf] = *(const short8v*)(qbase + (size_t)(rf * 16 + rl) * 256 + g * 8);
    #pragma unroll
    for (int mf = 0; mf < 4; ++mf)
      kf[mf] = *(const short8v*)(qbase + 128 + (size_t)(mf * 16 + rl) * 256 + g * 8);
  } else {
    #pragma unroll
    for (int i = 0; i < 4; ++i) { qf[i] = zz; kf[i] = zz; }
  }
  const f32x4 z = {0.f, 0.f, 0.f, 0.f};
  f32x4 s[4][4];
  #pragma unroll
  for (int mf = 0; mf < 4; ++mf)
    #pragma unroll
    for (int rf = 0; rf < 4; ++rf)
      s[mf][rf] = mfma32(kf[mf], qf[rf], z);   // S^T: m = mf*16+4g+e, r = rf*16+rl
  // ---- bias + softmax (m runs over lanes sharing rl: xor 16/32) ----
  float sum[4];
  #pragma unroll
  for (int rf = 0; rf < 4; ++rf) {
    const int r = rf * 16 + rl, i1 = r >> 3, j1 = r & 7;
    float mx = -1e30f;
    #pragma unroll
    for (int mf = 0; mf < 4; ++mf)
      #pragma unroll
      for (int e = 0; e < 4; ++e) {
        const int m = mf * 16 + g * 4 + e;
        const int i2 = m >> 3, j2 = m & 7;
        const float v = s[mf][rf][e] * 0.25f + Tb[((i1 - i2 + 7) * 15 + (j1 - j2 + 7)) * 8 + h];
        s[mf][rf][e] = v;
        mx = fmaxf(mx, v);
      }
    mx = fmaxf(mx, __shfl_xor(mx, 16));
    mx = fmaxf(mx, __shfl_xor(mx, 32));
    float sm = 0.f;
    #pragma unroll
    for (int mf = 0; mf < 4; ++mf)
      #pragma unroll
      for (int e = 0; e < 4; ++e) {
        const float ev = __expf(s[mf][rf][e] - mx);
        s[mf][rf][e] = ev;
        sm += ev;
      }
    sm += __shfl_xor(sm, 16);
    sm += __shfl_xor(sm, 32);
    sum[rf] = sm;
  }
  // ---- pack P to bf16 and round-trip through per-wave LDS (intra-wave, no barrier) ----
  char* Pw = (char*)&Pl[w][0];
  #pragma unroll
  for (int rf = 0; rf < 4; ++rf) {
    const int r = rf * 16 + rl;
    const int swz = (r & 7) << 4;
    #pragma unroll
    for (int mf = 0; mf < 4; ++mf) {
      uint2 u;
      u.x = (unsigned)f2bf(s[mf][rf][0]) | ((unsigned)f2bf(s[mf][rf][1]) << 16);
      u.y = (unsigned)f2bf(s[mf][rf][2]) | ((unsigned)f2bf(s[mf][rf][3]) << 16);
      *(uint2*)(Pw + ((r * 128 + mf * 32 + g * 8) ^ swz)) = u;
    }
  }
  // ---- PV: O^T = V^T (A) x P^T (B), K = 32, 2 K-blocks ----
  const unsigned short* vb = vt + (((size_t)win * 8 + h) << 10) + rl * 64 + g * 8;
  f32x4 o[4];
  #pragma unroll
  for (int rf = 0; rf < 4; ++rf) o[rf] = z;
  #pragma unroll
  for (int c = 0; c < 2; ++c) {
    const short8v va = *(const short8v*)(vb + c * 32);
    #pragma unroll
    for (int rf = 0; rf < 4; ++rf) {
      const int r = rf * 16 + rl;
      const short8v pb = *(const short8v*)(Pw + ((r * 128 + c * 64 + g * 16) ^ ((r & 7) << 4)));
      o[rf] = mfma32(va, pb, o[rf]);
    }
  }
  #pragma unroll
  for (int rf = 0; rf < 4; ++rf) {
    const float inv = 1.f / sum[rf];
    const int r = rf * 16 + rl;
    ushort4 ov = { f2bf(o[rf][0] * inv), f2bf(o[rf][1] * inv),
                   f2bf(o[rf][2] * inv), f2bf(o[rf][3] * inv) };
    *(ushort4*)(attn + ((size_t)win * 64 + r) * 128 + h * 16 + g * 4) = ov;
  }
}

// ---------------- K4: proj MFMA + window reverse + unshift + residual -> d_out (f32) ----------------
__global__ __launch_bounds__(256, 2) void k4_proj(
    const unsigned short* __restrict__ A,
    const unsigned short* __restrict__ Wb,
    const float* __restrict__ bias,
    const float* __restrict__ xin,
    float* __restrict__ out)
{
  __shared__ __align__(16) short At[128 * 128];
  __shared__ __align__(16) short Bt[128 * 128];
  const int t = threadIdx.x;
  const int row0 = blockIdx.x * 128;
  stage128(Wb, 128, At);
  stage128(A + (size_t)row0 * 128, 128, Bt);
  __syncthreads();
  const int l = t & 63, w = t >> 6, w0 = w & 1, w1 = w >> 1;
  const int g = l >> 4, rl = l & 15;
  const f32x4 z = {0.f, 0.f, 0.f, 0.f};
  f32x4 acc[4][4];
  #pragma unroll
  for (int i = 0; i < 4; ++i)
    #pragma unroll
    for (int j = 0; j < 4; ++j) acc[i][j] = z;
  #pragma unroll
  for (int kk = 0; kk < 4; ++kk) {
    short8v a[4], b[4];
    #pragma unroll
    for (int i = 0; i < 4; ++i) a[i] = frag_ld(At, w0 * 64 + i * 16 + rl, kk * 4 + g);
    #pragma unroll
    for (int j = 0; j < 4; ++j) b[j] = frag_ld(Bt, w1 * 64 + j * 16 + rl, kk * 4 + g);
    #pragma unroll
    for (int i = 0; i < 4; ++i)
      #pragma unroll
      for (int j = 0; j < 4; ++j)
        acc[i][j] = mfma32(a[i], b[j], acc[i][j]);
  }
  #pragma unroll
  for (int i = 0; i < 4; ++i) {
    const int c = w0 * 64 + i * 16 + 4 * g;
    const float4 bv = *(const float4*)(bias + c);
    #pragma unroll
    for (int j = 0; j < 4; ++j) {
      const int r = row0 + w1 * 64 + j * 16 + rl;
      const int wn = r >> 6, n = r & 63;
      const int b_ = wn >> 10, rem = wn & 1023;
      const int wh = rem >> 5, ww = rem & 31;
      const int si = n >> 3, sj = n & 7;
      const int hd = (wh * 8 + si + 4) & 255;
      const int wd = (ww * 8 + sj + 4) & 255;
      const size_t off = (((size_t)b_ << 16) + hd * 256 + wd) * 128 + c;
      const float4 xv = *(const float4*)(xin + off);
      float4 o = { xv.x + acc[i][j][0] + bv.x, xv.y + acc[i][j][1] + bv.y,
                   xv.z + acc[i][j][2] + bv.z, xv.w + acc[i][j][3] + bv.w };
      *(float4*)(out + off) = o;
    }
  }
}

// ---------------- K5: fused LN2 + fc1 + GELU + fc2 + residual (round-5 structure) ----------------
// Changes vs r5: (a) tanh GELU; (b) x2 kept in registers (v[32]/thread) and the epilogue
// round-trips oacc through the dead Wt LDS instead of re-reading x2 from global.
__global__ __launch_bounds__(256, 2) void k5_mlp(
    const float* x2,
    const float* __restrict__ gw, const float* __restrict__ gb,
    const unsigned short* __restrict__ w1b, const float* __restrict__ b1,
    const unsigned short* __restrict__ w2b, const float* __restrict__ b2,
    float* out)
{
  __shared__ __align__(16) short Xt[64 * 128];
  __shared__ __align__(16) short Ht[64 * 128];
  __shared__ __align__(16) short Wt[128 * 128];
  const int t = threadIdx.x;
  const size_t row0 = (size_t)blockIdx.x * 64;
  const int rr = t >> 2, qq = t & 3;
  float v[32];                                   // raw x2 values, kept live for residual
  {
    const float* src = x2 + (row0 + rr) * 128 + qq * 32;
    float s = 0.f, ss = 0.f;
    #pragma unroll
    for (int q = 0; q < 8; ++q) {
      const float4 a4 = *(const float4*)(src + q * 4);
      v[q*4+0] = a4.x; v[q*4+1] = a4.y; v[q*4+2] = a4.z; v[q*4+3] = a4.w;
      s  += a4.x + a4.y + a4.z + a4.w;
      ss += a4.x*a4.x + a4.y*a4.y + a4.z*a4.z + a4.w*a4.w;
    }
    s += __shfl_xor(s, 1); ss += __shfl_xor(ss, 1);
    s += __shfl_xor(s, 2); ss += __shfl_xor(ss, 2);
    const float mean = s * 0.0078125f;
    const float rstd = rsqrtf(ss * 0.0078125f - mean * mean + LNEPS);
    #pragma unroll
    for (int cc = 0; cc < 4; ++cc) {
      const int col = qq * 32 + cc * 8;
      const float4 g0 = *(const float4*)(gw + col), g1 = *(const float4*)(gw + col + 4);
      const float4 c0 = *(const float4*)(gb + col), c1 = *(const float4*)(gb + col + 4);
      uint4 pk;
      pk.x = (unsigned)f2bf((v[cc*8+0]-mean)*rstd*g0.x + c0.x)
           | ((unsigned)f2bf((v[cc*8+1]-mean)*rstd*g0.y + c0.y) << 16);
      pk.y = (unsigned)f2bf((v[cc*8+2]-mean)*rstd*g0.z + c0.z)
           | ((unsigned)f2bf((v[cc*8+3]-mean)*rstd*g0.w + c0.w) << 16);
      pk.z = (unsigned)f2bf((v[cc*8+4]-mean)*rstd*g1.x + c1.x)
           | ((unsigned)f2bf((v[cc*8+5]-mean)*rstd*g1.y + c1.y) << 16);
      pk.w = (unsigned)f2bf((v[cc*8+6]-mean)*rstd*g1.z + c1.z)
           | ((unsigned)f2bf((v[cc*8+7]-mean)*rstd*g1.w + c1.w) << 16);
      const int chunk = qq * 4 + cc;
      *(uint4*)((char*)Xt + rr * 256 + ((chunk ^ (rr & 7)) << 4)) = pk;
    }
  }
  const int l = t & 63, w = t >> 6, w0 = w & 1, w1 = w >> 1;
  const int g = l >> 4, rl = l & 15;
  const f32x4 z = {0.f, 0.f, 0.f, 0.f};
  f32x4 oacc[4][2];
  #pragma unroll
  for (int i = 0; i < 4; ++i) { oacc[i][0] = z; oacc[i][1] = z; }
  for (int sb = 0; sb < 4; ++sb) {
    __syncthreads();
    stage128(w1b + (size_t)sb * 128 * 128, 128, Wt);
    __syncthreads();
    f32x4 hacc[4][2];
    #pragma unroll
    for (int i = 0; i < 4; ++i) { hacc[i][0] = z; hacc[i][1] = z; }
    #pragma unroll
    for (int kk = 0; kk < 4; ++kk) {
      short8v a[4], b[2];
      #pragma unroll
      for (int i = 0; i < 4; ++i) a[i] = frag_ld(Wt, w0 * 64 + i * 16 + rl, kk * 4 + g);
      #pragma unroll
      for (int j = 0; j < 2; ++j) b[j] = frag_ld(Xt, w1 * 32 + j * 16 + rl, kk * 4 + g);
      #pragma unroll
      for (int i = 0; i < 4; ++i)
        #pragma unroll
        for (int j = 0; j < 2; ++j)
          hacc[i][j] = mfma32(a[i], b[j], hacc[i][j]);
    }
    __syncthreads();
    #pragma unroll
    for (int i = 0; i < 4; ++i) {
      const int cl = w0 * 64 + i * 16 + 4 * g;
      const float4 b1v = *(const float4*)(b1 + sb * 128 + cl);
      const float ba[4] = {b1v.x, b1v.y, b1v.z, b1v.w};
      #pragma unroll
      for (int j = 0; j < 2; ++j) {
        const int r = w1 * 32 + j * 16 + rl;
        ushort4 p;
        p.x = f2bf(gelu_f(hacc[i][j][0] + ba[0]));
        p.y = f2bf(gelu_f(hacc[i][j][1] + ba[1]));
        p.z = f2bf(gelu_f(hacc[i][j][2] + ba[2]));
        p.w = f2bf(gelu_f(hacc[i][j][3] + ba[3]));
        const int chunk = cl >> 3, inner = (cl & 7) * 2;
        *(ushort4*)((char*)Ht + r * 256 + ((chunk ^ (r & 7)) << 4) + inner) = p;
      }
    }
    stage128(w2b + (size_t)sb * 128, 512, Wt);
    __syncthreads();
    #pragma unroll
    for (int kk = 0; kk < 4; ++kk) {
      short8v a[4], b[2];
      #pragma unroll
      for (int i = 0; i < 4; ++i) a[i] = frag_ld(Wt, w0 * 64 + i * 16 + rl, kk * 4 + g);
      #pragma unroll
      for (int j = 0; j < 2; ++j) b[j] = frag_ld(Ht, w1 * 32 + j * 16 + rl, kk * 4 + g);
      #pragma unroll
      for (int i = 0; i < 4; ++i)
        #pragma unroll
        for (int j = 0; j < 2; ++j)
          oacc[i][j] = mfma32(a[i], b[j], oacc[i][j]);
    }
  }
  // ---- epilogue: oacc -> Wt(f32, swizzled) -> LN-layout threads add v + b2 ----
  __syncthreads();                    // last fc2 reads of Wt/Ht done
  float* Ot = (float*)Wt;             // 64 rows x 128 f32 = 32 KB (exact fit)
  #pragma unroll
  for (int i = 0; i < 4; ++i) {
    const int c4 = (w0 * 64 + i * 16 + 4 * g) >> 2;
    #pragma unroll
    for (int j = 0; j < 2; ++j) {
      const int r = w1 * 32 + j * 16 + rl;
      float4 o4 = { oacc[i][j][0], oacc[i][j][1], oacc[i][j][2], oacc[i][j][3] };
      *(float4*)((char*)Ot + r * 512 + ((c4 ^ (r & 7)) << 4)) = o4;
    }
  }
  __syncthreads();
  #pragma unroll
  for (int k = 0; k < 8; ++k) {
    const int c4 = qq * 8 + k;
    const float4 ov = *(const float4*)((char*)Ot + rr * 512 + ((c4 ^ (rr & 7)) << 4));
    const float4 bv = *(const float4*)(b2 + c4 * 4);
    float4 o = { v[k*4+0] + ov.x + bv.x, v[k*4+1] + ov.y + bv.y,
                 v[k*4+2] + ov.z + bv.z, v[k*4+3] + ov.w + bv.w };
    *(float4*)(out + (row0 + rr) * 128 + c4 * 4) = o;
  }
}

extern "C" void kernel_launch(void* const* d_in, const int* in_sizes, int n_in,
                              void* d_out, int out_size, void* d_ws, size_t ws_size,
                              hipStream_t stream)
{
  const float* x    = (const float*)d_in[0];
  const float* n1w  = (const float*)d_in[1];
  const float* n1b  = (const float*)d_in[2];
  const float* qkvw = (const float*)d_in[3];
  const float* qkvB = (const float*)d_in[4];
  const float* relb = (const float*)d_in[5];
  const float* pw   = (const float*)d_in[6];
  const float* pb   = (const float*)d_in[7];
  const float* n2w  = (const float*)d_in[8];
  const float* n2b  = (const float*)d_in[9];
  const float* w1   = (const float*)d_in[10];
  const float* b1   = (const float*)d_in[11];
  const float* w2   = (const float*)d_in[12];
  const float* b2   = (const float*)d_in[13];
  float* out = (float*)d_out;

  unsigned short* winb = (unsigned short*)d_ws;        // 16,777,216 el (LN1 out; reused as attn out)
  unsigned short* qkb  = winb + 16777216;              // 33,554,432 el  Q|K interleaved [row][256]
  unsigned short* vtb  = qkb + 33554432;               // 16,777,216 el  V^T per (win,head): [16][64]
  unsigned short* wb   = vtb + 16777216;               // 196,608 el  bf16 weights
  unsigned short* qkvw_b = wb;
  unsigned short* pw_b   = wb + 49152;
  unsigned short* w1_b   = wb + 65536;
  unsigned short* w2_b   = wb + 131072;

  k0_cvt<<<192, 256, 0, stream>>>(qkvw, pw, w1, w2, wb);
  k1_ln1_window<<<32768, 256, 0, stream>>>(x, n1w, n1b, winb);
  k2_qkv<<<dim3(1024, 3), 256, 0, stream>>>(winb, qkvw_b, qkvB, qkb, vtb);
  k3_attn<<<4096, 256, 0, stream>>>(qkb, vtb, relb, winb);
  k4_proj<<<1024, 256, 0, stream>>>(winb, pw_b, pb, x, out);
  k5_mlp<<<2048, 256, 0, stream>>>(out, n2w, n2b, w1_b, b1, w2_b, b2, out);
}

// Round 9
// 229.140 us; speedup vs baseline: 1.5599x; 1.4106x over previous
//
#include <hip/hip_runtime.h>
#include <hip/hip_bf16.h>
#include <cmath>

#define LNEPS 1e-5f

typedef __attribute__((ext_vector_type(8))) short short8v;
typedef __attribute__((ext_vector_type(4))) float f32x4;

__device__ __forceinline__ unsigned short f2bf(float f){
  unsigned u = __float_as_uint(f);
  u += 0x7fffu + ((u >> 16) & 1u);
  return (unsigned short)(u >> 16);
}
__device__ __forceinline__ float gelu_f(float x){
  return 0.5f * x * (1.f + erff(x * 0.70710678118654752f));   // exact (r5-proven)
}

// Device-guarded MFMA wrapper: host pass must never see target builtins.
__device__ __forceinline__ f32x4 mfma32(short8v a, short8v b, f32x4 c){
#ifdef __HIP_DEVICE_COMPILE__
  return __builtin_amdgcn_mfma_f32_16x16x32_bf16(a, b, c, 0, 0, 0);
#else
  return c;
#endif
}

// Stage 128 rows x 128 bf16 from global [r][ldg] into XOR-swizzled LDS (row stride 256B).
__device__ __forceinline__ void stage128(const unsigned short* g, int ldg, short* lds){
  const int t = threadIdx.x;
  #pragma unroll
  for (int it = 0; it < 8; ++it) {
    const int flat = it * 256 + t;
    const int r = flat >> 4, c = flat & 15;
    const uint4 v = *(const uint4*)(g + (size_t)r * ldg + c * 8);
    *(uint4*)((char*)lds + r * 256 + ((c ^ (r & 7)) << 4)) = v;
  }
}
// Swizzled 16B fragment read: row-major [row][128 bf16] (256B rows).
__device__ __forceinline__ short8v frag_ld(const short* lds, int row, int chunk){
  return *(const short8v*)((const char*)lds + row * 256 + ((chunk ^ (row & 7)) << 4));
}

// ---------------- K0: weights f32 -> bf16 ----------------
__global__ __launch_bounds__(256) void k0_cvt(
    const float* __restrict__ qkvw, const float* __restrict__ pw,
    const float* __restrict__ w1, const float* __restrict__ w2,
    unsigned short* __restrict__ dst)
{
  const int i = (blockIdx.x * 256 + threadIdx.x) * 4;
  const float* src; int off;
  if (i < 49152)       { src = qkvw; off = i; }
  else if (i < 65536)  { src = pw;   off = i - 49152; }
  else if (i < 131072) { src = w1;   off = i - 65536; }
  else                 { src = w2;   off = i - 131072; }
  const float4 v = *(const float4*)(src + off);
  ushort4 o = { f2bf(v.x), f2bf(v.y), f2bf(v.z), f2bf(v.w) };
  *(ushort4*)(dst + i) = o;
}

// ---------------- K2: fused LN1+shift+window staging + qkv MFMA GEMM ----------------
// Block owns 128 window-rows; A-tile built with LN computed in-flight; loops over
// the 3 128-col weight tiles (Q|K -> qk interleaved, V -> vt transposed).
__global__ __launch_bounds__(256, 2) void k2_qkv(
    const float* __restrict__ x,
    const float* __restrict__ gw, const float* __restrict__ gb,
    const unsigned short* __restrict__ Wb,
    const float* __restrict__ bias,
    unsigned short* __restrict__ qk,
    unsigned short* __restrict__ vt)
{
  __shared__ __align__(16) short At[128 * 128];   // weight tile (per nt)
  __shared__ __align__(16) short Bt[128 * 128];   // ln1(x) window-rows
  const int t = threadIdx.x;
  const int row0 = blockIdx.x * 128;
  // ---- LN1 + shift + window partition directly into Bt (16 threads/row x 8 f32) ----
  #pragma unroll
  for (int it = 0; it < 8; ++it) {
    const int flat = it * 256 + t;
    const int r = flat >> 4, c = flat & 15;
    const int row = row0 + r;
    const int wid = row >> 6, n = row & 63;
    const int b = wid >> 10, rem = wid & 1023;
    const int wh = rem >> 5, wwi = rem & 31;
    const int i = n >> 3, j = n & 7;
    const int sh = (wh * 8 + i + 4) & 255;
    const int sw = (wwi * 8 + j + 4) & 255;
    const float* src = x + (((size_t)b << 16) + sh * 256 + sw) * 128 + c * 8;
    const float4 a0 = *(const float4*)src;
    const float4 a1 = *(const float4*)(src + 4);
    float s  = a0.x + a0.y + a0.z + a0.w + a1.x + a1.y + a1.z + a1.w;
    float ss = a0.x*a0.x + a0.y*a0.y + a0.z*a0.z + a0.w*a0.w
             + a1.x*a1.x + a1.y*a1.y + a1.z*a1.z + a1.w*a1.w;
    s += __shfl_xor(s, 1); ss += __shfl_xor(ss, 1);
    s += __shfl_xor(s, 2); ss += __shfl_xor(ss, 2);
    s += __shfl_xor(s, 4); ss += __shfl_xor(ss, 4);
    s += __shfl_xor(s, 8); ss += __shfl_xor(ss, 8);
    const float mean = s * 0.0078125f;
    const float rstd = rsqrtf(ss * 0.0078125f - mean * mean + LNEPS);
    const float4 g0 = *(const float4*)(gw + c * 8), g1 = *(const float4*)(gw + c * 8 + 4);
    const float4 c0 = *(const float4*)(gb + c * 8), c1 = *(const float4*)(gb + c * 8 + 4);
    uint4 pk;
    pk.x = (unsigned)f2bf((a0.x - mean) * rstd * g0.x + c0.x)
         | ((unsigned)f2bf((a0.y - mean) * rstd * g0.y + c0.y) << 16);
    pk.y = (unsigned)f2bf((a0.z - mean) * rstd * g0.z + c0.z)
         | ((unsigned)f2bf((a0.w - mean) * rstd * g0.w + c0.w) << 16);
    pk.z = (unsigned)f2bf((a1.x - mean) * rstd * g1.x + c1.x)
         | ((unsigned)f2bf((a1.y - mean) * rstd * g1.y + c1.y) << 16);
    pk.w = (unsigned)f2bf((a1.z - mean) * rstd * g1.z + c1.z)
         | ((unsigned)f2bf((a1.w - mean) * rstd * g1.w + c1.w) << 16);
    *(uint4*)((char*)Bt + r * 256 + ((c ^ (r & 7)) << 4)) = pk;
  }
  stage128(Wb, 128, At);                     // weight tile nt=0
  __syncthreads();

  const int l = t & 63, w = t >> 6, w0 = w & 1, w1 = w >> 1;
  const int g = l >> 4, rl = l & 15;
  const f32x4 z = {0.f, 0.f, 0.f, 0.f};

  for (int nt = 0; nt < 3; ++nt) {
    f32x4 acc[4][4];
    #pragma unroll
    for (int i = 0; i < 4; ++i)
      #pragma unroll
      for (int j = 0; j < 4; ++j) acc[i][j] = z;
    #pragma unroll
    for (int kk = 0; kk < 4; ++kk) {
      short8v a[4], b[4];
      #pragma unroll
      for (int i = 0; i < 4; ++i) a[i] = frag_ld(At, w0 * 64 + i * 16 + rl, kk * 4 + g);
      #pragma unroll
      for (int j = 0; j < 4; ++j) b[j] = frag_ld(Bt, w1 * 64 + j * 16 + rl, kk * 4 + g);
      #pragma unroll
      for (int i = 0; i < 4; ++i)
        #pragma unroll
        for (int j = 0; j < 4; ++j)
          acc[i][j] = mfma32(a[i], b[j], acc[i][j]);
    }
    if (nt < 2) {
      const int n0 = nt * 128;
      #pragma unroll
      for (int i = 0; i < 4; ++i) {
        const int np = w0 * 64 + i * 16 + 4 * g;
        const float4 bv = *(const float4*)(bias + n0 + np);
        #pragma unroll
        for (int j = 0; j < 4; ++j) {
          const int r = row0 + w1 * 64 + j * 16 + rl;
          ushort4 o = { f2bf(acc[i][j][0] + bv.x), f2bf(acc[i][j][1] + bv.y),
                        f2bf(acc[i][j][2] + bv.z), f2bf(acc[i][j][3] + bv.w) };
          *(ushort4*)(qk + (size_t)r * 256 + n0 + np) = o;
        }
      }
    } else {
      #pragma unroll
      for (int i = 0; i < 4; ++i) {
        const int np = w0 * 64 + i * 16 + 4 * g;
        const int h = np >> 4, db = np & 15;
        const float4 bv = *(const float4*)(bias + 256 + np);
        const float ba[4] = {bv.x, bv.y, bv.z, bv.w};
        #pragma unroll
        for (int j = 0; j < 4; ++j) {
          const int r = row0 + w1 * 64 + j * 16 + rl;
          const int wn = r >> 6, m = r & 63;
          unsigned short* dst = vt + (((size_t)wn * 8 + h) << 10) + m;
          #pragma unroll
          for (int e = 0; e < 4; ++e)
            dst[(db + e) * 64] = f2bf(acc[i][j][e] + ba[e]);
        }
      }
    }
    if (nt < 2) {
      __syncthreads();                         // At reads done
      stage128(Wb + (size_t)(nt + 1) * 16384, 128, At);
      __syncthreads();                         // next tile ready
    }
  }
}

// ---------------- K3: MFMA window attention (16x16x32 only), one wave per (window, head) ----------------
__global__ __launch_bounds__(256, 2) void k3_attn(
    const unsigned short* __restrict__ qk,
    const unsigned short* __restrict__ vt,
    const float* __restrict__ table,
    unsigned short* __restrict__ attn)
{
  __shared__ float Tb[1800];
  __shared__ __align__(16) unsigned short Pl[4][4096];   // per-wave P [r][m] bf16, XOR-swizzled
  const int t = threadIdx.x;
  for (int i = t; i < 1800; i += 256) Tb[i] = table[i];
  __syncthreads();
  const int l = t & 63, w = t >> 6;
  const int id = blockIdx.x * 4 + w;
  const int win = id >> 3, h = id & 7;
  const int g = l >> 4, rl = l & 15;
  // ---- QK^T via 16x16x32, K zero-padded (head_dim = 16 -> lanes g>=2 hold zeros) ----
  const unsigned short* qbase = qk + (size_t)win * 64 * 256 + h * 16;
  const short8v zz = {0,0,0,0,0,0,0,0};
  short8v qf[4], kf[4];
  if (g < 2) {
    #pragma unroll
    for (int rf = 0; rf < 4; ++rf)
      qf[rf] = *(const short8v*)(qbase + (size_t)(rf * 16 + rl) * 256 + g * 8);
    #pragma unroll
    for (int mf = 0; mf < 4; ++mf)
      kf[mf] = *(const short8v*)(qbase + 128 + (size_t)(mf * 16 + rl) * 256 + g * 8);
  } else {
    #pragma unroll
    for (int i = 0; i < 4; ++i) { qf[i] = zz; kf[i] = zz; }
  }
  const f32x4 z = {0.f, 0.f, 0.f, 0.f};
  f32x4 s[4][4];
  #pragma unroll
  for (int mf = 0; mf < 4; ++mf)
    #pragma unroll
    for (int rf = 0; rf < 4; ++rf)
      s[mf][rf] = mfma32(kf[mf], qf[rf], z);   // S^T: m = mf*16+4g+e, r = rf*16+rl
  // ---- bias + softmax (m runs over lanes sharing rl: xor 16/32) ----
  float sum[4];
  #pragma unroll
  for (int rf = 0; rf < 4; ++rf) {
    const int r = rf * 16 + rl, i1 = r >> 3, j1 = r & 7;
    float mx = -1e30f;
    #pragma unroll
    for (int mf = 0; mf < 4; ++mf)
      #pragma unroll
      for (int e = 0; e < 4; ++e) {
        const int m = mf * 16 + g * 4 + e;
        const int i2 = m >> 3, j2 = m & 7;
        const float v = s[mf][rf][e] * 0.25f + Tb[((i1 - i2 + 7) * 15 + (j1 - j2 + 7)) * 8 + h];
        s[mf][rf][e] = v;
        mx = fmaxf(mx, v);
      }
    mx = fmaxf(mx, __shfl_xor(mx, 16));
    mx = fmaxf(mx, __shfl_xor(mx, 32));
    float sm = 0.f;
    #pragma unroll
    for (int mf = 0; mf < 4; ++mf)
      #pragma unroll
      for (int e = 0; e < 4; ++e) {
        const float ev = __expf(s[mf][rf][e] - mx);
        s[mf][rf][e] = ev;
        sm += ev;
      }
    sm += __shfl_xor(sm, 16);
    sm += __shfl_xor(sm, 32);
    sum[rf] = sm;
  }
  // ---- pack P to bf16 and round-trip through per-wave LDS (intra-wave, no barrier) ----
  char* Pw = (char*)&Pl[w][0];
  #pragma unroll
  for (int rf = 0; rf < 4; ++rf) {
    const int r = rf * 16 + rl;
    const int swz = (r & 7) << 4;
    #pragma unroll
    for (int mf = 0; mf < 4; ++mf) {
      uint2 u;
      u.x = (unsigned)f2bf(s[mf][rf][0]) | ((unsigned)f2bf(s[mf][rf][1]) << 16);
      u.y = (unsigned)f2bf(s[mf][rf][2]) | ((unsigned)f2bf(s[mf][rf][3]) << 16);
      *(uint2*)(Pw + ((r * 128 + mf * 32 + g * 8) ^ swz)) = u;
    }
  }
  // ---- PV: O^T = V^T (A) x P^T (B), K = 32, 2 K-blocks ----
  const unsigned short* vb = vt + (((size_t)win * 8 + h) << 10) + rl * 64 + g * 8;
  f32x4 o[4];
  #pragma unroll
  for (int rf = 0; rf < 4; ++rf) o[rf] = z;
  #pragma unroll
  for (int c = 0; c < 2; ++c) {
    const short8v va = *(const short8v*)(vb + c * 32);
    #pragma unroll
    for (int rf = 0; rf < 4; ++rf) {
      const int r = rf * 16 + rl;
      const short8v pb = *(const short8v*)(Pw + ((r * 128 + c * 64 + g * 16) ^ ((r & 7) << 4)));
      o[rf] = mfma32(va, pb, o[rf]);
    }
  }
  #pragma unroll
  for (int rf = 0; rf < 4; ++rf) {
    const float inv = 1.f / sum[rf];
    const int r = rf * 16 + rl;
    ushort4 ov = { f2bf(o[rf][0] * inv), f2bf(o[rf][1] * inv),
                   f2bf(o[rf][2] * inv), f2bf(o[rf][3] * inv) };
    *(ushort4*)(attn + ((size_t)win * 64 + r) * 128 + h * 16 + g * 4) = ov;
  }
}

// ---------------- K4: proj MFMA + window reverse + unshift + residual -> d_out (f32) ----------------
__global__ __launch_bounds__(256, 2) void k4_proj(
    const unsigned short* __restrict__ A,
    const unsigned short* __restrict__ Wb,
    const float* __restrict__ bias,
    const float* __restrict__ xin,
    float* __restrict__ out)
{
  __shared__ __align__(16) short At[128 * 128];
  __shared__ __align__(16) short Bt[128 * 128];
  const int t = threadIdx.x;
  const int row0 = blockIdx.x * 128;
  stage128(Wb, 128, At);
  stage128(A + (size_t)row0 * 128, 128, Bt);
  __syncthreads();
  const int l = t & 63, w = t >> 6, w0 = w & 1, w1 = w >> 1;
  const int g = l >> 4, rl = l & 15;
  const f32x4 z = {0.f, 0.f, 0.f, 0.f};
  f32x4 acc[4][4];
  #pragma unroll
  for (int i = 0; i < 4; ++i)
    #pragma unroll
    for (int j = 0; j < 4; ++j) acc[i][j] = z;
  #pragma unroll
  for (int kk = 0; kk < 4; ++kk) {
    short8v a[4], b[4];
    #pragma unroll
    for (int i = 0; i < 4; ++i) a[i] = frag_ld(At, w0 * 64 + i * 16 + rl, kk * 4 + g);
    #pragma unroll
    for (int j = 0; j < 4; ++j) b[j] = frag_ld(Bt, w1 * 64 + j * 16 + rl, kk * 4 + g);
    #pragma unroll
    for (int i = 0; i < 4; ++i)
      #pragma unroll
      for (int j = 0; j < 4; ++j)
        acc[i][j] = mfma32(a[i], b[j], acc[i][j]);
  }
  #pragma unroll
  for (int i = 0; i < 4; ++i) {
    const int c = w0 * 64 + i * 16 + 4 * g;
    const float4 bv = *(const float4*)(bias + c);
    #pragma unroll
    for (int j = 0; j < 4; ++j) {
      const int r = row0 + w1 * 64 + j * 16 + rl;
      const int wn = r >> 6, n = r & 63;
      const int b_ = wn >> 10, rem = wn & 1023;
      const int wh = rem >> 5, ww = rem & 31;
      const int si = n >> 3, sj = n & 7;
      const int hd = (wh * 8 + si + 4) & 255;
      const int wd = (ww * 8 + sj + 4) & 255;
      const size_t off = (((size_t)b_ << 16) + hd * 256 + wd) * 128 + c;
      const float4 xv = *(const float4*)(xin + off);
      float4 o = { xv.x + acc[i][j][0] + bv.x, xv.y + acc[i][j][1] + bv.y,
                   xv.z + acc[i][j][2] + bv.z, xv.w + acc[i][j][3] + bv.w };
      *(float4*)(out + off) = o;
    }
  }
}

// ---------------- K5: fused LN2 + fc1 + GELU + fc2 + residual (exact r5 structure) ----------------
__global__ __launch_bounds__(256, 2) void k5_mlp(
    const float* x2,
    const float* __restrict__ gw, const float* __restrict__ gb,
    const unsigned short* __restrict__ w1b, const float* __restrict__ b1,
    const unsigned short* __restrict__ w2b, const float* __restrict__ b2,
    float* out)
{
  __shared__ __align__(16) short Xt[64 * 128];
  __shared__ __align__(16) short Ht[64 * 128];
  __shared__ __align__(16) short Wt[128 * 128];
  const int t = threadIdx.x;
  const size_t row0 = (size_t)blockIdx.x * 64;
  {
    const int rr = t >> 2, qq = t & 3;
    const float* src = x2 + (row0 + rr) * 128 + qq * 32;
    float v[32]; float s = 0.f, ss = 0.f;
    #pragma unroll
    for (int q = 0; q < 8; ++q) {
      const float4 a4 = *(const float4*)(src + q * 4);
      v[q*4+0] = a4.x; v[q*4+1] = a4.y; v[q*4+2] = a4.z; v[q*4+3] = a4.w;
      s  += a4.x + a4.y + a4.z + a4.w;
      ss += a4.x*a4.x + a4.y*a4.y + a4.z*a4.z + a4.w*a4.w;
    }
    s += __shfl_xor(s, 1); ss += __shfl_xor(ss, 1);
    s += __shfl_xor(s, 2); ss += __shfl_xor(ss, 2);
    const float mean = s * 0.0078125f;
    const float rstd = rsqrtf(ss * 0.0078125f - mean * mean + LNEPS);
    #pragma unroll
    for (int cc = 0; cc < 4; ++cc) {
      const int col = qq * 32 + cc * 8;
      const float4 g0 = *(const float4*)(gw + col), g1 = *(const float4*)(gw + col + 4);
      const float4 c0 = *(const float4*)(gb + col), c1 = *(const float4*)(gb + col + 4);
      uint4 pk;
      pk.x = (unsigned)f2bf((v[cc*8+0]-mean)*rstd*g0.x + c0.x)
           | ((unsigned)f2bf((v[cc*8+1]-mean)*rstd*g0.y + c0.y) << 16);
      pk.y = (unsigned)f2bf((v[cc*8+2]-mean)*rstd*g0.z + c0.z)
           | ((unsigned)f2bf((v[cc*8+3]-mean)*rstd*g0.w + c0.w) << 16);
      pk.z = (unsigned)f2bf((v[cc*8+4]-mean)*rstd*g1.x + c1.x)
           | ((unsigned)f2bf((v[cc*8+5]-mean)*rstd*g1.y + c1.y) << 16);
      pk.w = (unsigned)f2bf((v[cc*8+6]-mean)*rstd*g1.z + c1.z)
           | ((unsigned)f2bf((v[cc*8+7]-mean)*rstd*g1.w + c1.w) << 16);
      const int chunk = qq * 4 + cc;
      *(uint4*)((char*)Xt + rr * 256 + ((chunk ^ (rr & 7)) << 4)) = pk;
    }
  }
  const int l = t & 63, w = t >> 6, w0 = w & 1, w1 = w >> 1;
  const int g = l >> 4, rl = l & 15;
  const f32x4 z = {0.f, 0.f, 0.f, 0.f};
  f32x4 oacc[4][2];
  #pragma unroll
  for (int i = 0; i < 4; ++i) { oacc[i][0] = z; oacc[i][1] = z; }
  for (int sb = 0; sb < 4; ++sb) {
    __syncthreads();
    stage128(w1b + (size_t)sb * 128 * 128, 128, Wt);
    __syncthreads();
    f32x4 hacc[4][2];
    #pragma unroll
    for (int i = 0; i < 4; ++i) { hacc[i][0] = z; hacc[i][1] = z; }
    #pragma unroll
    for (int kk = 0; kk < 4; ++kk) {
      short8v a[4], b[2];
      #pragma unroll
      for (int i = 0; i < 4; ++i) a[i] = frag_ld(Wt, w0 * 64 + i * 16 + rl, kk * 4 + g);
      #pragma unroll
      for (int j = 0; j < 2; ++j) b[j] = frag_ld(Xt, w1 * 32 + j * 16 + rl, kk * 4 + g);
      #pragma unroll
      for (int i = 0; i < 4; ++i)
        #pragma unroll
        for (int j = 0; j < 2; ++j)
          hacc[i][j] = mfma32(a[i], b[j], hacc[i][j]);
    }
    __syncthreads();
    #pragma unroll
    for (int i = 0; i < 4; ++i) {
      const int cl = w0 * 64 + i * 16 + 4 * g;
      const float4 b1v = *(const float4*)(b1 + sb * 128 + cl);
      const float ba[4] = {b1v.x, b1v.y, b1v.z, b1v.w};
      #pragma unroll
      for (int j = 0; j < 2; ++j) {
        const int r = w1 * 32 + j * 16 + rl;
        ushort4 p;
        p.x = f2bf(gelu_f(hacc[i][j][0] + ba[0]));
        p.y = f2bf(gelu_f(hacc[i][j][1] + ba[1]));
        p.z = f2bf(gelu_f(hacc[i][j][2] + ba[2]));
        p.w = f2bf(gelu_f(hacc[i][j][3] + ba[3]));
        const int chunk = cl >> 3, inner = (cl & 7) * 2;
        *(ushort4*)((char*)Ht + r * 256 + ((chunk ^ (r & 7)) << 4) + inner) = p;
      }
    }
    stage128(w2b + (size_t)sb * 128, 512, Wt);
    __syncthreads();
    #pragma unroll
    for (int kk = 0; kk < 4; ++kk) {
      short8v a[4], b[2];
      #pragma unroll
      for (int i = 0; i < 4; ++i) a[i] = frag_ld(Wt, w0 * 64 + i * 16 + rl, kk * 4 + g);
      #pragma unroll
      for (int j = 0; j < 2; ++j) b[j] = frag_ld(Ht, w1 * 32 + j * 16 + rl, kk * 4 + g);
      #pragma unroll
      for (int i = 0; i < 4; ++i)
        #pragma unroll
        for (int j = 0; j < 2; ++j)
          oacc[i][j] = mfma32(a[i], b[j], oacc[i][j]);
    }
  }
  #pragma unroll
  for (int i = 0; i < 4; ++i) {
    const int c = w0 * 64 + i * 16 + 4 * g;
    const float4 bv = *(const float4*)(b2 + c);
    #pragma unroll
    for (int j = 0; j < 2; ++j) {
      const size_t r = row0 + w1 * 32 + j * 16 + rl;
      const float4 xv = *(const float4*)(x2 + r * 128 + c);
      float4 o = { xv.x + oacc[i][j][0] + bv.x, xv.y + oacc[i][j][1] + bv.y,
                   xv.z + oacc[i][j][2] + bv.z, xv.w + oacc[i][j][3] + bv.w };
      *(float4*)(out + r * 128 + c) = o;
    }
  }
}

extern "C" void kernel_launch(void* const* d_in, const int* in_sizes, int n_in,
                              void* d_out, int out_size, void* d_ws, size_t ws_size,
                              hipStream_t stream)
{
  const float* x    = (const float*)d_in[0];
  const float* n1w  = (const float*)d_in[1];
  const float* n1b  = (const float*)d_in[2];
  const float* qkvw = (const float*)d_in[3];
  const float* qkvB = (const float*)d_in[4];
  const float* relb = (const float*)d_in[5];
  const float* pw   = (const float*)d_in[6];
  const float* pb   = (const float*)d_in[7];
  const float* n2w  = (const float*)d_in[8];
  const float* n2b  = (const float*)d_in[9];
  const float* w1   = (const float*)d_in[10];
  const float* b1   = (const float*)d_in[11];
  const float* w2   = (const float*)d_in[12];
  const float* b2   = (const float*)d_in[13];
  float* out = (float*)d_out;

  unsigned short* winb = (unsigned short*)d_ws;        // 16,777,216 el  attn out
  unsigned short* qkb  = winb + 16777216;              // 33,554,432 el  Q|K interleaved [row][256]
  unsigned short* vtb  = qkb + 33554432;               // 16,777,216 el  V^T per (win,head): [16][64]
  unsigned short* wb   = vtb + 16777216;               // 196,608 el  bf16 weights
  unsigned short* qkvw_b = wb;
  unsigned short* pw_b   = wb + 49152;
  unsigned short* w1_b   = wb + 65536;
  unsigned short* w2_b   = wb + 131072;

  k0_cvt<<<192, 256, 0, stream>>>(qkvw, pw, w1, w2, wb);
  k2_qkv<<<1024, 256, 0, stream>>>(x, n1w, n1b, qkvw_b, qkvB, qkb, vtb);
  k3_attn<<<4096, 256, 0, stream>>>(qkb, vtb, relb, winb);
  k4_proj<<<1024, 256, 0, stream>>>(winb, pw_b, pb, x, out);
  k5_mlp<<<2048, 256, 0, stream>>>(out, n2w, n2b, w1_b, b1, w2_b, b2, out);
}

// Round 10
// 217.793 us; speedup vs baseline: 1.6411x; 1.0521x over previous
//
#include <hip/hip_runtime.h>
#include <hip/hip_bf16.h>
#include <cmath>

#define LNEPS 1e-5f

typedef __attribute__((ext_vector_type(8))) short short8v;
typedef __attribute__((ext_vector_type(4))) float f32x4;

__device__ __forceinline__ unsigned short f2bf(float f){
  unsigned u = __float_as_uint(f);
  u += 0x7fffu + ((u >> 16) & 1u);
  return (unsigned short)(u >> 16);
}
__device__ __forceinline__ float gelu_f(float x){
  return 0.5f * x * (1.f + erff(x * 0.70710678118654752f));   // exact; used for LUT build
}

// Device-guarded MFMA wrapper: host pass must never see target builtins.
__device__ __forceinline__ f32x4 mfma32(short8v a, short8v b, f32x4 c){
#ifdef __HIP_DEVICE_COMPILE__
  return __builtin_amdgcn_mfma_f32_16x16x32_bf16(a, b, c, 0, 0, 0);
#else
  return c;
#endif
}

// Stage 128 rows x 128 bf16 global [r][ldg] -> LDS via global_load_lds (16B, direct).
// LDS layout is byte-identical to the old swizzled stage128: linear dest slot `flat`
// receives global chunk (r, c^(r&7)) -- XOR swizzle applied on the SOURCE address
// (involution), so frag_ld() is unchanged.
__device__ __forceinline__ void stage128(const unsigned short* g, int ldg, short* lds){
#ifdef __HIP_DEVICE_COMPILE__
  const int t = threadIdx.x;
  const int wv = t >> 6;
  #pragma unroll
  for (int it = 0; it < 8; ++it) {
    const int flat = it * 256 + t;
    const int r = flat >> 4, c = flat & 15;
    const unsigned short* src = g + (size_t)r * ldg + ((c ^ (r & 7)) << 3);
    short* dst = lds + (size_t)(it * 256 + wv * 64) * 8;    // wave-uniform base, lane x16B
    __builtin_amdgcn_global_load_lds(
        (const __attribute__((address_space(1))) void*)src,
        (__attribute__((address_space(3))) void*)dst, 16, 0, 0);
  }
#else
  (void)g; (void)ldg; (void)lds;
#endif
}
// Swizzled 16B fragment read: row-major [row][128 bf16] (256B rows).
__device__ __forceinline__ short8v frag_ld(const short* lds, int row, int chunk){
  return *(const short8v*)((const char*)lds + row * 256 + ((chunk ^ (row & 7)) << 4));
}

// ---------------- K0: weights f32 -> bf16 ----------------
__global__ __launch_bounds__(256) void k0_cvt(
    const float* __restrict__ qkvw, const float* __restrict__ pw,
    const float* __restrict__ w1, const float* __restrict__ w2,
    unsigned short* __restrict__ dst)
{
  const int i = (blockIdx.x * 256 + threadIdx.x) * 4;
  const float* src; int off;
  if (i < 49152)       { src = qkvw; off = i; }
  else if (i < 65536)  { src = pw;   off = i - 49152; }
  else if (i < 131072) { src = w1;   off = i - 65536; }
  else                 { src = w2;   off = i - 131072; }
  const float4 v = *(const float4*)(src + off);
  ushort4 o = { f2bf(v.x), f2bf(v.y), f2bf(v.z), f2bf(v.w) };
  *(ushort4*)(dst + i) = o;
}

// ---------------- K2: fused LN1+shift+window staging + qkv MFMA GEMM ----------------
__global__ __launch_bounds__(256, 2) void k2_qkv(
    const float* __restrict__ x,
    const float* __restrict__ gw, const float* __restrict__ gb,
    const unsigned short* __restrict__ Wb,
    const float* __restrict__ bias,
    unsigned short* __restrict__ qk,
    unsigned short* __restrict__ vt)
{
  __shared__ __align__(16) short At[128 * 128];   // weight tile (per nt)
  __shared__ __align__(16) short Bt[128 * 128];   // ln1(x) window-rows
  const int t = threadIdx.x;
  const int row0 = blockIdx.x * 128;
  stage128(Wb, 128, At);                     // async: flies under the LN below
  // ---- LN1 + shift + window partition directly into Bt (16 threads/row x 8 f32) ----
  #pragma unroll
  for (int it = 0; it < 8; ++it) {
    const int flat = it * 256 + t;
    const int r = flat >> 4, c = flat & 15;
    const int row = row0 + r;
    const int wid = row >> 6, n = row & 63;
    const int b = wid >> 10, rem = wid & 1023;
    const int wh = rem >> 5, wwi = rem & 31;
    const int i = n >> 3, j = n & 7;
    const int sh = (wh * 8 + i + 4) & 255;
    const int sw = (wwi * 8 + j + 4) & 255;
    const float* src = x + (((size_t)b << 16) + sh * 256 + sw) * 128 + c * 8;
    const float4 a0 = *(const float4*)src;
    const float4 a1 = *(const float4*)(src + 4);
    float s  = a0.x + a0.y + a0.z + a0.w + a1.x + a1.y + a1.z + a1.w;
    float ss = a0.x*a0.x + a0.y*a0.y + a0.z*a0.z + a0.w*a0.w
             + a1.x*a1.x + a1.y*a1.y + a1.z*a1.z + a1.w*a1.w;
    s += __shfl_xor(s, 1); ss += __shfl_xor(ss, 1);
    s += __shfl_xor(s, 2); ss += __shfl_xor(ss, 2);
    s += __shfl_xor(s, 4); ss += __shfl_xor(ss, 4);
    s += __shfl_xor(s, 8); ss += __shfl_xor(ss, 8);
    const float mean = s * 0.0078125f;
    const float rstd = rsqrtf(ss * 0.0078125f - mean * mean + LNEPS);
    const float4 g0 = *(const float4*)(gw + c * 8), g1 = *(const float4*)(gw + c * 8 + 4);
    const float4 c0 = *(const float4*)(gb + c * 8), c1 = *(const float4*)(gb + c * 8 + 4);
    uint4 pk;
    pk.x = (unsigned)f2bf((a0.x - mean) * rstd * g0.x + c0.x)
         | ((unsigned)f2bf((a0.y - mean) * rstd * g0.y + c0.y) << 16);
    pk.y = (unsigned)f2bf((a0.z - mean) * rstd * g0.z + c0.z)
         | ((unsigned)f2bf((a0.w - mean) * rstd * g0.w + c0.w) << 16);
    pk.z = (unsigned)f2bf((a1.x - mean) * rstd * g1.x + c1.x)
         | ((unsigned)f2bf((a1.y - mean) * rstd * g1.y + c1.y) << 16);
    pk.w = (unsigned)f2bf((a1.z - mean) * rstd * g1.z + c1.z)
         | ((unsigned)f2bf((a1.w - mean) * rstd * g1.w + c1.w) << 16);
    *(uint4*)((char*)Bt + r * 256 + ((c ^ (r & 7)) << 4)) = pk;
  }
  __syncthreads();

  const int l = t & 63, w = t >> 6, w0 = w & 1, w1 = w >> 1;
  const int g = l >> 4, rl = l & 15;
  const f32x4 z = {0.f, 0.f, 0.f, 0.f};

  for (int nt = 0; nt < 3; ++nt) {
    f32x4 acc[4][4];
    #pragma unroll
    for (int i = 0; i < 4; ++i)
      #pragma unroll
      for (int j = 0; j < 4; ++j) acc[i][j] = z;
    #pragma unroll
    for (int kk = 0; kk < 4; ++kk) {
      short8v a[4], b[4];
      #pragma unroll
      for (int i = 0; i < 4; ++i) a[i] = frag_ld(At, w0 * 64 + i * 16 + rl, kk * 4 + g);
      #pragma unroll
      for (int j = 0; j < 4; ++j) b[j] = frag_ld(Bt, w1 * 64 + j * 16 + rl, kk * 4 + g);
      #pragma unroll
      for (int i = 0; i < 4; ++i)
        #pragma unroll
        for (int j = 0; j < 4; ++j)
          acc[i][j] = mfma32(a[i], b[j], acc[i][j]);
    }
    if (nt < 2) {
      const int n0 = nt * 128;
      #pragma unroll
      for (int i = 0; i < 4; ++i) {
        const int np = w0 * 64 + i * 16 + 4 * g;
        const float4 bv = *(const float4*)(bias + n0 + np);
        #pragma unroll
        for (int j = 0; j < 4; ++j) {
          const int r = row0 + w1 * 64 + j * 16 + rl;
          ushort4 o = { f2bf(acc[i][j][0] + bv.x), f2bf(acc[i][j][1] + bv.y),
                        f2bf(acc[i][j][2] + bv.z), f2bf(acc[i][j][3] + bv.w) };
          *(ushort4*)(qk + (size_t)r * 256 + n0 + np) = o;
        }
      }
    } else {
      #pragma unroll
      for (int i = 0; i < 4; ++i) {
        const int np = w0 * 64 + i * 16 + 4 * g;
        const int h = np >> 4, db = np & 15;
        const float4 bv = *(const float4*)(bias + 256 + np);
        const float ba[4] = {bv.x, bv.y, bv.z, bv.w};
        #pragma unroll
        for (int j = 0; j < 4; ++j) {
          const int r = row0 + w1 * 64 + j * 16 + rl;
          const int wn = r >> 6, m = r & 63;
          unsigned short* dst = vt + (((size_t)wn * 8 + h) << 10) + m;
          #pragma unroll
          for (int e = 0; e < 4; ++e)
            dst[(db + e) * 64] = f2bf(acc[i][j][e] + ba[e]);
        }
      }
    }
    if (nt < 2) {
      __syncthreads();                         // At reads done
      stage128(Wb + (size_t)(nt + 1) * 16384, 128, At);
      __syncthreads();                         // next tile ready
    }
  }
}

// ---------------- K3: MFMA window attention (16x16x32 only), one wave per (window, head) ----------------
__global__ __launch_bounds__(256, 2) void k3_attn(
    const unsigned short* __restrict__ qk,
    const unsigned short* __restrict__ vt,
    const float* __restrict__ table,
    unsigned short* __restrict__ attn)
{
  __shared__ float Tb[1800];
  __shared__ __align__(16) unsigned short Pl[4][4096];   // per-wave P [r][m] bf16, XOR-swizzled
  const int t = threadIdx.x;
  for (int i = t; i < 1800; i += 256) Tb[i] = table[i];
  __syncthreads();
  const int l = t & 63, w = t >> 6;
  const int id = blockIdx.x * 4 + w;
  const int win = id >> 3, h = id & 7;
  const int g = l >> 4, rl = l & 15;
  // ---- QK^T via 16x16x32, K zero-padded (head_dim = 16 -> lanes g>=2 hold zeros) ----
  const unsigned short* qbase = qk + (size_t)win * 64 * 256 + h * 16;
  const short8v zz = {0,0,0,0,0,0,0,0};
  short8v qf[4], kf[4];
  if (g < 2) {
    #pragma unroll
    for (int rf = 0; rf < 4; ++rf)
      qf[rf] = *(const short8v*)(qbase + (size_t)(rf * 16 + rl) * 256 + g * 8);
    #pragma unroll
    for (int mf = 0; mf < 4; ++mf)
      kf[mf] = *(const short8v*)(qbase + 128 + (size_t)(mf * 16 + rl) * 256 + g * 8);
  } else {
    #pragma unroll
    for (int i = 0; i < 4; ++i) { qf[i] = zz; kf[i] = zz; }
  }
  const f32x4 z = {0.f, 0.f, 0.f, 0.f};
  f32x4 s[4][4];
  #pragma unroll
  for (int mf = 0; mf < 4; ++mf)
    #pragma unroll
    for (int rf = 0; rf < 4; ++rf)
      s[mf][rf] = mfma32(kf[mf], qf[rf], z);   // S^T: m = mf*16+4g+e, r = rf*16+rl
  // ---- bias + softmax (m runs over lanes sharing rl: xor 16/32) ----
  float sum[4];
  #pragma unroll
  for (int rf = 0; rf < 4; ++rf) {
    const int r = rf * 16 + rl, i1 = r >> 3, j1 = r & 7;
    float mx = -1e30f;
    #pragma unroll
    for (int mf = 0; mf < 4; ++mf)
      #pragma unroll
      for (int e = 0; e < 4; ++e) {
        const int m = mf * 16 + g * 4 + e;
        const int i2 = m >> 3, j2 = m & 7;
        const float v = s[mf][rf][e] * 0.25f + Tb[((i1 - i2 + 7) * 15 + (j1 - j2 + 7)) * 8 + h];
        s[mf][rf][e] = v;
        mx = fmaxf(mx, v);
      }
    mx = fmaxf(mx, __shfl_xor(mx, 16));
    mx = fmaxf(mx, __shfl_xor(mx, 32));
    float sm = 0.f;
    #pragma unroll
    for (int mf = 0; mf < 4; ++mf)
      #pragma unroll
      for (int e = 0; e < 4; ++e) {
        const float ev = __expf(s[mf][rf][e] - mx);
        s[mf][rf][e] = ev;
        sm += ev;
      }
    sm += __shfl_xor(sm, 16);
    sm += __shfl_xor(sm, 32);
    sum[rf] = sm;
  }
  // ---- pack P to bf16 and round-trip through per-wave LDS (intra-wave, no barrier) ----
  char* Pw = (char*)&Pl[w][0];
  #pragma unroll
  for (int rf = 0; rf < 4; ++rf) {
    const int r = rf * 16 + rl;
    const int swz = (r & 7) << 4;
    #pragma unroll
    for (int mf = 0; mf < 4; ++mf) {
      uint2 u;
      u.x = (unsigned)f2bf(s[mf][rf][0]) | ((unsigned)f2bf(s[mf][rf][1]) << 16);
      u.y = (unsigned)f2bf(s[mf][rf][2]) | ((unsigned)f2bf(s[mf][rf][3]) << 16);
      *(uint2*)(Pw + ((r * 128 + mf * 32 + g * 8) ^ swz)) = u;
    }
  }
  // ---- PV: O^T = V^T (A) x P^T (B), K = 32, 2 K-blocks ----
  const unsigned short* vb = vt + (((size_t)win * 8 + h) << 10) + rl * 64 + g * 8;
  f32x4 o[4];
  #pragma unroll
  for (int rf = 0; rf < 4; ++rf) o[rf] = z;
  #pragma unroll
  for (int c = 0; c < 2; ++c) {
    const short8v va = *(const short8v*)(vb + c * 32);
    #pragma unroll
    for (int rf = 0; rf < 4; ++rf) {
      const int r = rf * 16 + rl;
      const short8v pb = *(const short8v*)(Pw + ((r * 128 + c * 64 + g * 16) ^ ((r & 7) << 4)));
      o[rf] = mfma32(va, pb, o[rf]);
    }
  }
  #pragma unroll
  for (int rf = 0; rf < 4; ++rf) {
    const float inv = 1.f / sum[rf];
    const int r = rf * 16 + rl;
    ushort4 ov = { f2bf(o[rf][0] * inv), f2bf(o[rf][1] * inv),
                   f2bf(o[rf][2] * inv), f2bf(o[rf][3] * inv) };
    *(ushort4*)(attn + ((size_t)win * 64 + r) * 128 + h * 16 + g * 4) = ov;
  }
}

// ---------------- K4: proj MFMA + window reverse + unshift + residual -> d_out (f32) ----------------
__global__ __launch_bounds__(256, 2) void k4_proj(
    const unsigned short* __restrict__ A,
    const unsigned short* __restrict__ Wb,
    const float* __restrict__ bias,
    const float* __restrict__ xin,
    float* __restrict__ out)
{
  __shared__ __align__(16) short At[128 * 128];
  __shared__ __align__(16) short Bt[128 * 128];
  const int t = threadIdx.x;
  const int row0 = blockIdx.x * 128;
  stage128(Wb, 128, At);
  stage128(A + (size_t)row0 * 128, 128, Bt);
  __syncthreads();
  const int l = t & 63, w = t >> 6, w0 = w & 1, w1 = w >> 1;
  const int g = l >> 4, rl = l & 15;
  const f32x4 z = {0.f, 0.f, 0.f, 0.f};
  f32x4 acc[4][4];
  #pragma unroll
  for (int i = 0; i < 4; ++i)
    #pragma unroll
    for (int j = 0; j < 4; ++j) acc[i][j] = z;
  #pragma unroll
  for (int kk = 0; kk < 4; ++kk) {
    short8v a[4], b[4];
    #pragma unroll
    for (int i = 0; i < 4; ++i) a[i] = frag_ld(At, w0 * 64 + i * 16 + rl, kk * 4 + g);
    #pragma unroll
    for (int j = 0; j < 4; ++j) b[j] = frag_ld(Bt, w1 * 64 + j * 16 + rl, kk * 4 + g);
    #pragma unroll
    for (int i = 0; i < 4; ++i)
      #pragma unroll
      for (int j = 0; j < 4; ++j)
        acc[i][j] = mfma32(a[i], b[j], acc[i][j]);
  }
  #pragma unroll
  for (int i = 0; i < 4; ++i) {
    const int c = w0 * 64 + i * 16 + 4 * g;
    const float4 bv = *(const float4*)(bias + c);
    #pragma unroll
    for (int j = 0; j < 4; ++j) {
      const int r = row0 + w1 * 64 + j * 16 + rl;
      const int wn = r >> 6, n = r & 63;
      const int b_ = wn >> 10, rem = wn & 1023;
      const int wh = rem >> 5, ww = rem & 31;
      const int si = n >> 3, sj = n & 7;
      const int hd = (wh * 8 + si + 4) & 255;
      const int wd = (ww * 8 + sj + 4) & 255;
      const size_t off = (((size_t)b_ << 16) + hd * 256 + wd) * 128 + c;
      const float4 xv = *(const float4*)(xin + off);
      float4 o = { xv.x + acc[i][j][0] + bv.x, xv.y + acc[i][j][1] + bv.y,
                   xv.z + acc[i][j][2] + bv.z, xv.w + acc[i][j][3] + bv.w };
      *(float4*)(out + off) = o;
    }
  }
}

// ---------------- K5: fused LN2 + fc1 + GELU + fc2 + residual (r5 skeleton + LUT GELU + async staging) ----------------
__global__ __launch_bounds__(256, 2) void k5_mlp(
    const float* x2,
    const float* __restrict__ gw, const float* __restrict__ gb,
    const unsigned short* __restrict__ w1b, const float* __restrict__ b1,
    const unsigned short* __restrict__ w2b, const float* __restrict__ b2,
    float* out)
{
  __shared__ __align__(16) short Xt[64 * 128];
  __shared__ __align__(16) short Ht[64 * 128];
  __shared__ __align__(16) short Wt[128 * 128];
  __shared__ float2 Gt[1024];                 // GELU LUT: (value, delta) over [-4,4), step 1/128
  const int t = threadIdx.x;
  const size_t row0 = (size_t)blockIdx.x * 64;
  #pragma unroll
  for (int i = t; i < 1024; i += 256) {
    const float x0 = (float)i * 0.0078125f - 4.f;
    const float g0 = gelu_f(x0);
    Gt[i] = make_float2(g0, gelu_f(x0 + 0.0078125f) - g0);
  }
  {
    const int rr = t >> 2, qq = t & 3;
    const float* src = x2 + (row0 + rr) * 128 + qq * 32;
    float v[32]; float s = 0.f, ss = 0.f;
    #pragma unroll
    for (int q = 0; q < 8; ++q) {
      const float4 a4 = *(const float4*)(src + q * 4);
      v[q*4+0] = a4.x; v[q*4+1] = a4.y; v[q*4+2] = a4.z; v[q*4+3] = a4.w;
      s  += a4.x + a4.y + a4.z + a4.w;
      ss += a4.x*a4.x + a4.y*a4.y + a4.z*a4.z + a4.w*a4.w;
    }
    s += __shfl_xor(s, 1); ss += __shfl_xor(ss, 1);
    s += __shfl_xor(s, 2); ss += __shfl_xor(ss, 2);
    const float mean = s * 0.0078125f;
    const float rstd = rsqrtf(ss * 0.0078125f - mean * mean + LNEPS);
    #pragma unroll
    for (int cc = 0; cc < 4; ++cc) {
      const int col = qq * 32 + cc * 8;
      const float4 g0 = *(const float4*)(gw + col), g1 = *(const float4*)(gw + col + 4);
      const float4 c0 = *(const float4*)(gb + col), c1 = *(const float4*)(gb + col + 4);
      uint4 pk;
      pk.x = (unsigned)f2bf((v[cc*8+0]-mean)*rstd*g0.x + c0.x)
           | ((unsigned)f2bf((v[cc*8+1]-mean)*rstd*g0.y + c0.y) << 16);
      pk.y = (unsigned)f2bf((v[cc*8+2]-mean)*rstd*g0.z + c0.z)
           | ((unsigned)f2bf((v[cc*8+3]-mean)*rstd*g0.w + c0.w) << 16);
      pk.z = (unsigned)f2bf((v[cc*8+4]-mean)*rstd*g1.x + c1.x)
           | ((unsigned)f2bf((v[cc*8+5]-mean)*rstd*g1.y + c1.y) << 16);
      pk.w = (unsigned)f2bf((v[cc*8+6]-mean)*rstd*g1.z + c1.z)
           | ((unsigned)f2bf((v[cc*8+7]-mean)*rstd*g1.w + c1.w) << 16);
      const int chunk = qq * 4 + cc;
      *(uint4*)((char*)Xt + rr * 256 + ((chunk ^ (rr & 7)) << 4)) = pk;
    }
  }
  const int l = t & 63, w = t >> 6, w0 = w & 1, w1 = w >> 1;
  const int g = l >> 4, rl = l & 15;
  const f32x4 z = {0.f, 0.f, 0.f, 0.f};
  f32x4 oacc[4][2];
  #pragma unroll
  for (int i = 0; i < 4; ++i) { oacc[i][0] = z; oacc[i][1] = z; }
  for (int sb = 0; sb < 4; ++sb) {
    __syncthreads();
    stage128(w1b + (size_t)sb * 128 * 128, 128, Wt);
    __syncthreads();
    f32x4 hacc[4][2];
    #pragma unroll
    for (int i = 0; i < 4; ++i) { hacc[i][0] = z; hacc[i][1] = z; }
    #pragma unroll
    for (int kk = 0; kk < 4; ++kk) {
      short8v a[4], b[2];
      #pragma unroll
      for (int i = 0; i < 4; ++i) a[i] = frag_ld(Wt, w0 * 64 + i * 16 + rl, kk * 4 + g);
      #pragma unroll
      for (int j = 0; j < 2; ++j) b[j] = frag_ld(Xt, w1 * 32 + j * 16 + rl, kk * 4 + g);
      #pragma unroll
      for (int i = 0; i < 4; ++i)
        #pragma unroll
        for (int j = 0; j < 2; ++j)
          hacc[i][j] = mfma32(a[i], b[j], hacc[i][j]);
    }
    __syncthreads();
    #pragma unroll
    for (int i = 0; i < 4; ++i) {
      const int cl = w0 * 64 + i * 16 + 4 * g;
      const float4 b1v = *(const float4*)(b1 + sb * 128 + cl);
      const float ba[4] = {b1v.x, b1v.y, b1v.z, b1v.w};
      #pragma unroll
      for (int j = 0; j < 2; ++j) {
        const int r = w1 * 32 + j * 16 + rl;
        unsigned short pe[4];
        #pragma unroll
        for (int e = 0; e < 4; ++e) {
          const float xh = hacc[i][j][e] + ba[e];
          float tq = fmaf(xh, 128.f, 512.f);
          tq = fminf(fmaxf(tq, 0.f), 1023.99f);
          const float fi = floorf(tq);
          const float2 ent = Gt[(int)fi];
          float gv = fmaf(tq - fi, ent.y, ent.x);
          gv = xh > 3.98f ? xh : gv;
          pe[e] = f2bf(gv);
        }
        ushort4 p = { pe[0], pe[1], pe[2], pe[3] };
        const int chunk = cl >> 3, inner = (cl & 7) * 2;
        *(ushort4*)((char*)Ht + r * 256 + ((chunk ^ (r & 7)) << 4) + inner) = p;
      }
    }
    stage128(w2b + (size_t)sb * 128, 512, Wt);
    __syncthreads();
    #pragma unroll
    for (int kk = 0; kk < 4; ++kk) {
      short8v a[4], b[2];
      #pragma unroll
      for (int i = 0; i < 4; ++i) a[i] = frag_ld(Wt, w0 * 64 + i * 16 + rl, kk * 4 + g);
      #pragma unroll
      for (int j = 0; j < 2; ++j) b[j] = frag_ld(Ht, w1 * 32 + j * 16 + rl, kk * 4 + g);
      #pragma unroll
      for (int i = 0; i < 4; ++i)
        #pragma unroll
        for (int j = 0; j < 2; ++j)
          oacc[i][j] = mfma32(a[i], b[j], oacc[i][j]);
    }
  }
  #pragma unroll
  for (int i = 0; i < 4; ++i) {
    const int c = w0 * 64 + i * 16 + 4 * g;
    const float4 bv = *(const float4*)(b2 + c);
    #pragma unroll
    for (int j = 0; j < 2; ++j) {
      const size_t r = row0 + w1 * 32 + j * 16 + rl;
      const float4 xv = *(const float4*)(x2 + r * 128 + c);
      float4 o = { xv.x + oacc[i][j][0] + bv.x, xv.y + oacc[i][j][1] + bv.y,
                   xv.z + oacc[i][j][2] + bv.z, xv.w + oacc[i][j][3] + bv.w };
      *(float4*)(out + r * 128 + c) = o;
    }
  }
}

extern "C" void kernel_launch(void* const* d_in, const int* in_sizes, int n_in,
                              void* d_out, int out_size, void* d_ws, size_t ws_size,
                              hipStream_t stream)
{
  const float* x    = (const float*)d_in[0];
  const float* n1w  = (const float*)d_in[1];
  const float* n1b  = (const float*)d_in[2];
  const float* qkvw = (const float*)d_in[3];
  const float* qkvB = (const float*)d_in[4];
  const float* relb = (const float*)d_in[5];
  const float* pw   = (const float*)d_in[6];
  const float* pb   = (const float*)d_in[7];
  const float* n2w  = (const float*)d_in[8];
  const float* n2b  = (const float*)d_in[9];
  const float* w1   = (const float*)d_in[10];
  const float* b1   = (const float*)d_in[11];
  const float* w2   = (const float*)d_in[12];
  const float* b2   = (const float*)d_in[13];
  float* out = (float*)d_out;

  unsigned short* winb = (unsigned short*)d_ws;        // 16,777,216 el  attn out
  unsigned short* qkb  = winb + 16777216;              // 33,554,432 el  Q|K interleaved [row][256]
  unsigned short* vtb  = qkb + 33554432;               // 16,777,216 el  V^T per (win,head): [16][64]
  unsigned short* wb   = vtb + 16777216;               // 196,608 el  bf16 weights
  unsigned short* qkvw_b = wb;
  unsigned short* pw_b   = wb + 49152;
  unsigned short* w1_b   = wb + 65536;
  unsigned short* w2_b   = wb + 131072;

  k0_cvt<<<192, 256, 0, stream>>>(qkvw, pw, w1, w2, wb);
  k2_qkv<<<1024, 256, 0, stream>>>(x, n1w, n1b, qkvw_b, qkvB, qkb, vtb);
  k3_attn<<<4096, 256, 0, stream>>>(qkb, vtb, relb, winb);
  k4_proj<<<1024, 256, 0, stream>>>(winb, pw_b, pb, x, out);
  k5_mlp<<<2048, 256, 0, stream>>>(out, n2w, n2b, w1_b, b1, w2_b, b2, out);
}

// Round 11
// 182.294 us; speedup vs baseline: 1.9607x; 1.1947x over previous
//
#include <hip/hip_runtime.h>
#include <hip/hip_bf16.h>
#include <cmath>

#define LNEPS 1e-5f

typedef __attribute__((ext_vector_type(8))) short short8v;
typedef __attribute__((ext_vector_type(4))) float f32x4;

__device__ __forceinline__ unsigned short f2bf(float f){
  unsigned u = __float_as_uint(f);
  u += 0x7fffu + ((u >> 16) & 1u);
  return (unsigned short)(u >> 16);
}
__device__ __forceinline__ float gelu_f(float x){
  return 0.5f * x * (1.f + erff(x * 0.70710678118654752f));   // exact; used for LUT build
}

// Device-guarded MFMA wrapper: host pass must never see target builtins.
__device__ __forceinline__ f32x4 mfma32(short8v a, short8v b, f32x4 c){
#ifdef __HIP_DEVICE_COMPILE__
  return __builtin_amdgcn_mfma_f32_16x16x32_bf16(a, b, c, 0, 0, 0);
#else
  return c;
#endif
}

// Stage 128 rows x 128 bf16 global [r][ldg] -> LDS via global_load_lds (16B, direct).
// XOR swizzle applied on the SOURCE address (involution) -> frag_ld unchanged.
__device__ __forceinline__ void stage128(const unsigned short* g, int ldg, short* lds){
#ifdef __HIP_DEVICE_COMPILE__
  const int t = threadIdx.x;
  const int wv = t >> 6;
  #pragma unroll
  for (int it = 0; it < 8; ++it) {
    const int flat = it * 256 + t;
    const int r = flat >> 4, c = flat & 15;
    const unsigned short* src = g + (size_t)r * ldg + ((c ^ (r & 7)) << 3);
    short* dst = lds + (size_t)(it * 256 + wv * 64) * 8;
    __builtin_amdgcn_global_load_lds(
        (const __attribute__((address_space(1))) void*)src,
        (__attribute__((address_space(3))) void*)dst, 16, 0, 0);
  }
#else
  (void)g; (void)ldg; (void)lds;
#endif
}
// Stage 64 rows x 128 bf16 (ldg = 128), same layout/swizzle convention.
__device__ __forceinline__ void stage64(const unsigned short* g, short* lds){
#ifdef __HIP_DEVICE_COMPILE__
  const int t = threadIdx.x;
  const int wv = t >> 6;
  #pragma unroll
  for (int it = 0; it < 4; ++it) {
    const int flat = it * 256 + t;
    const int r = flat >> 4, c = flat & 15;
    const unsigned short* src = g + (size_t)r * 128 + ((c ^ (r & 7)) << 3);
    short* dst = lds + (size_t)(it * 256 + wv * 64) * 8;
    __builtin_amdgcn_global_load_lds(
        (const __attribute__((address_space(1))) void*)src,
        (__attribute__((address_space(3))) void*)dst, 16, 0, 0);
  }
#else
  (void)g; (void)lds;
#endif
}
// Swizzled 16B fragment read: row-major [row][128 bf16] (256B rows).
__device__ __forceinline__ short8v frag_ld(const short* lds, int row, int chunk){
  return *(const short8v*)((const char*)lds + row * 256 + ((chunk ^ (row & 7)) << 4));
}

// ---------------- K0: weights f32 -> bf16 ----------------
__global__ __launch_bounds__(256) void k0_cvt(
    const float* __restrict__ qkvw, const float* __restrict__ pw,
    const float* __restrict__ w1, const float* __restrict__ w2,
    unsigned short* __restrict__ dst)
{
  const int i = (blockIdx.x * 256 + threadIdx.x) * 4;
  const float* src; int off;
  if (i < 49152)       { src = qkvw; off = i; }
  else if (i < 65536)  { src = pw;   off = i - 49152; }
  else if (i < 131072) { src = w1;   off = i - 65536; }
  else                 { src = w2;   off = i - 131072; }
  const float4 v = *(const float4*)(src + off);
  ushort4 o = { f2bf(v.x), f2bf(v.y), f2bf(v.z), f2bf(v.w) };
  *(ushort4*)(dst + i) = o;
}

// ---------------- K2: fused LN1+shift+window staging + qkv MFMA GEMM ----------------
__global__ __launch_bounds__(256, 2) void k2_qkv(
    const float* __restrict__ x,
    const float* __restrict__ gw, const float* __restrict__ gb,
    const unsigned short* __restrict__ Wb,
    const float* __restrict__ bias,
    unsigned short* __restrict__ qk,
    unsigned short* __restrict__ vt)
{
  __shared__ __align__(16) short At[128 * 128];   // weight tile (per nt)
  __shared__ __align__(16) short Bt[128 * 128];   // ln1(x) window-rows
  const int t = threadIdx.x;
  const int row0 = blockIdx.x * 128;
  stage128(Wb, 128, At);                     // async: flies under the LN below
  #pragma unroll
  for (int it = 0; it < 8; ++it) {
    const int flat = it * 256 + t;
    const int r = flat >> 4, c = flat & 15;
    const int row = row0 + r;
    const int wid = row >> 6, n = row & 63;
    const int b = wid >> 10, rem = wid & 1023;
    const int wh = rem >> 5, wwi = rem & 31;
    const int i = n >> 3, j = n & 7;
    const int sh = (wh * 8 + i + 4) & 255;
    const int sw = (wwi * 8 + j + 4) & 255;
    const float* src = x + (((size_t)b << 16) + sh * 256 + sw) * 128 + c * 8;
    const float4 a0 = *(const float4*)src;
    const float4 a1 = *(const float4*)(src + 4);
    float s  = a0.x + a0.y + a0.z + a0.w + a1.x + a1.y + a1.z + a1.w;
    float ss = a0.x*a0.x + a0.y*a0.y + a0.z*a0.z + a0.w*a0.w
             + a1.x*a1.x + a1.y*a1.y + a1.z*a1.z + a1.w*a1.w;
    s += __shfl_xor(s, 1); ss += __shfl_xor(ss, 1);
    s += __shfl_xor(s, 2); ss += __shfl_xor(ss, 2);
    s += __shfl_xor(s, 4); ss += __shfl_xor(ss, 4);
    s += __shfl_xor(s, 8); ss += __shfl_xor(ss, 8);
    const float mean = s * 0.0078125f;
    const float rstd = rsqrtf(ss * 0.0078125f - mean * mean + LNEPS);
    const float4 g0 = *(const float4*)(gw + c * 8), g1 = *(const float4*)(gw + c * 8 + 4);
    const float4 c0 = *(const float4*)(gb + c * 8), c1 = *(const float4*)(gb + c * 8 + 4);
    uint4 pk;
    pk.x = (unsigned)f2bf((a0.x - mean) * rstd * g0.x + c0.x)
         | ((unsigned)f2bf((a0.y - mean) * rstd * g0.y + c0.y) << 16);
    pk.y = (unsigned)f2bf((a0.z - mean) * rstd * g0.z + c0.z)
         | ((unsigned)f2bf((a0.w - mean) * rstd * g0.w + c0.w) << 16);
    pk.z = (unsigned)f2bf((a1.x - mean) * rstd * g1.x + c1.x)
         | ((unsigned)f2bf((a1.y - mean) * rstd * g1.y + c1.y) << 16);
    pk.w = (unsigned)f2bf((a1.z - mean) * rstd * g1.z + c1.z)
         | ((unsigned)f2bf((a1.w - mean) * rstd * g1.w + c1.w) << 16);
    *(uint4*)((char*)Bt + r * 256 + ((c ^ (r & 7)) << 4)) = pk;
  }
  __syncthreads();

  const int l = t & 63, w = t >> 6, w0 = w & 1, w1 = w >> 1;
  const int g = l >> 4, rl = l & 15;
  const f32x4 z = {0.f, 0.f, 0.f, 0.f};

  for (int nt = 0; nt < 3; ++nt) {
    f32x4 acc[4][4];
    #pragma unroll
    for (int i = 0; i < 4; ++i)
      #pragma unroll
      for (int j = 0; j < 4; ++j) acc[i][j] = z;
    #pragma unroll
    for (int kk = 0; kk < 4; ++kk) {
      short8v a[4], b[4];
      #pragma unroll
      for (int i = 0; i < 4; ++i) a[i] = frag_ld(At, w0 * 64 + i * 16 + rl, kk * 4 + g);
      #pragma unroll
      for (int j = 0; j < 4; ++j) b[j] = frag_ld(Bt, w1 * 64 + j * 16 + rl, kk * 4 + g);
      #pragma unroll
      for (int i = 0; i < 4; ++i)
        #pragma unroll
        for (int j = 0; j < 4; ++j)
          acc[i][j] = mfma32(a[i], b[j], acc[i][j]);
    }
    if (nt < 2) {
      const int n0 = nt * 128;
      #pragma unroll
      for (int i = 0; i < 4; ++i) {
        const int np = w0 * 64 + i * 16 + 4 * g;
        const float4 bv = *(const float4*)(bias + n0 + np);
        #pragma unroll
        for (int j = 0; j < 4; ++j) {
          const int r = row0 + w1 * 64 + j * 16 + rl;
          ushort4 o = { f2bf(acc[i][j][0] + bv.x), f2bf(acc[i][j][1] + bv.y),
                        f2bf(acc[i][j][2] + bv.z), f2bf(acc[i][j][3] + bv.w) };
          *(ushort4*)(qk + (size_t)r * 256 + n0 + np) = o;
        }
      }
    } else {
      #pragma unroll
      for (int i = 0; i < 4; ++i) {
        const int np = w0 * 64 + i * 16 + 4 * g;
        const int h = np >> 4, db = np & 15;
        const float4 bv = *(const float4*)(bias + 256 + np);
        const float ba[4] = {bv.x, bv.y, bv.z, bv.w};
        #pragma unroll
        for (int j = 0; j < 4; ++j) {
          const int r = row0 + w1 * 64 + j * 16 + rl;
          const int wn = r >> 6, m = r & 63;
          unsigned short* dst = vt + (((size_t)wn * 8 + h) << 10) + m;
          #pragma unroll
          for (int e = 0; e < 4; ++e)
            dst[(db + e) * 64] = f2bf(acc[i][j][e] + ba[e]);
        }
      }
    }
    if (nt < 2) {
      __syncthreads();
      stage128(Wb + (size_t)(nt + 1) * 16384, 128, At);
      __syncthreads();
    }
  }
}

// ---------------- K3: MFMA window attention (16x16x32 only), one wave per (window, head) ----------------
__global__ __launch_bounds__(256, 2) void k3_attn(
    const unsigned short* __restrict__ qk,
    const unsigned short* __restrict__ vt,
    const float* __restrict__ table,
    unsigned short* __restrict__ attn)
{
  __shared__ float Tb[1800];
  __shared__ __align__(16) unsigned short Pl[4][4096];
  const int t = threadIdx.x;
  for (int i = t; i < 1800; i += 256) Tb[i] = table[i];
  __syncthreads();
  const int l = t & 63, w = t >> 6;
  const int id = blockIdx.x * 4 + w;
  const int win = id >> 3, h = id & 7;
  const int g = l >> 4, rl = l & 15;
  const unsigned short* qbase = qk + (size_t)win * 64 * 256 + h * 16;
  const short8v zz = {0,0,0,0,0,0,0,0};
  short8v qf[4], kf[4];
  if (g < 2) {
    #pragma unroll
    for (int rf = 0; rf < 4; ++rf)
      qf[rf] = *(const short8v*)(qbase + (size_t)(rf * 16 + rl) * 256 + g * 8);
    #pragma unroll
    for (int mf = 0; mf < 4; ++mf)
      kf[mf] = *(const short8v*)(qbase + 128 + (size_t)(mf * 16 + rl) * 256 + g * 8);
  } else {
    #pragma unroll
    for (int i = 0; i < 4; ++i) { qf[i] = zz; kf[i] = zz; }
  }
  const f32x4 z = {0.f, 0.f, 0.f, 0.f};
  f32x4 s[4][4];
  #pragma unroll
  for (int mf = 0; mf < 4; ++mf)
    #pragma unroll
    for (int rf = 0; rf < 4; ++rf)
      s[mf][rf] = mfma32(kf[mf], qf[rf], z);
  float sum[4];
  #pragma unroll
  for (int rf = 0; rf < 4; ++rf) {
    const int r = rf * 16 + rl, i1 = r >> 3, j1 = r & 7;
    float mx = -1e30f;
    #pragma unroll
    for (int mf = 0; mf < 4; ++mf)
      #pragma unroll
      for (int e = 0; e < 4; ++e) {
        const int m = mf * 16 + g * 4 + e;
        const int i2 = m >> 3, j2 = m & 7;
        const float v = s[mf][rf][e] * 0.25f + Tb[((i1 - i2 + 7) * 15 + (j1 - j2 + 7)) * 8 + h];
        s[mf][rf][e] = v;
        mx = fmaxf(mx, v);
      }
    mx = fmaxf(mx, __shfl_xor(mx, 16));
    mx = fmaxf(mx, __shfl_xor(mx, 32));
    float sm = 0.f;
    #pragma unroll
    for (int mf = 0; mf < 4; ++mf)
      #pragma unroll
      for (int e = 0; e < 4; ++e) {
        const float ev = __expf(s[mf][rf][e] - mx);
        s[mf][rf][e] = ev;
        sm += ev;
      }
    sm += __shfl_xor(sm, 16);
    sm += __shfl_xor(sm, 32);
    sum[rf] = sm;
  }
  char* Pw = (char*)&Pl[w][0];
  #pragma unroll
  for (int rf = 0; rf < 4; ++rf) {
    const int r = rf * 16 + rl;
    const int swz = (r & 7) << 4;
    #pragma unroll
    for (int mf = 0; mf < 4; ++mf) {
      uint2 u;
      u.x = (unsigned)f2bf(s[mf][rf][0]) | ((unsigned)f2bf(s[mf][rf][1]) << 16);
      u.y = (unsigned)f2bf(s[mf][rf][2]) | ((unsigned)f2bf(s[mf][rf][3]) << 16);
      *(uint2*)(Pw + ((r * 128 + mf * 32 + g * 8) ^ swz)) = u;
    }
  }
  const unsigned short* vb = vt + (((size_t)win * 8 + h) << 10) + rl * 64 + g * 8;
  f32x4 o[4];
  #pragma unroll
  for (int rf = 0; rf < 4; ++rf) o[rf] = z;
  #pragma unroll
  for (int c = 0; c < 2; ++c) {
    const short8v va = *(const short8v*)(vb + c * 32);
    #pragma unroll
    for (int rf = 0; rf < 4; ++rf) {
      const int r = rf * 16 + rl;
      const short8v pb = *(const short8v*)(Pw + ((r * 128 + c * 64 + g * 16) ^ ((r & 7) << 4)));
      o[rf] = mfma32(va, pb, o[rf]);
    }
  }
  #pragma unroll
  for (int rf = 0; rf < 4; ++rf) {
    const float inv = 1.f / sum[rf];
    const int r = rf * 16 + rl;
    ushort4 ov = { f2bf(o[rf][0] * inv), f2bf(o[rf][1] * inv),
                   f2bf(o[rf][2] * inv), f2bf(o[rf][3] * inv) };
    *(ushort4*)(attn + ((size_t)win * 64 + r) * 128 + h * 16 + g * 4) = ov;
  }
}

// ---------------- K45: fused proj + unshift-residual + LN2 + fc1 + GELU + fc2 + residual ----------------
// Block owns 64 window-rows. x2 lives only in registers; out written once at the
// scattered (window-reversed) positions. Thread mapping of proj acc is congruent
// with fc2's oacc, so residual adds are register-local.
__global__ __launch_bounds__(256, 2) void k45_proj_mlp(
    const unsigned short* __restrict__ A,      // attn out [131072][128] bf16
    const unsigned short* __restrict__ pwb,    // proj W bf16 (128,128)
    const float* __restrict__ pb,
    const float* __restrict__ xin,             // original x
    const float* __restrict__ gw, const float* __restrict__ gb,   // norm2
    const unsigned short* __restrict__ w1b, const float* __restrict__ b1,
    const unsigned short* __restrict__ w2b, const float* __restrict__ b2,
    float* __restrict__ out)
{
  __shared__ __align__(16) short Xt[64 * 128];   // ln2(x2) bf16
  __shared__ __align__(16) short Ht[64 * 128];   // attn staging, then h
  __shared__ __align__(16) short Wt[128 * 128];  // projW -> W1 -> W2
  __shared__ float2 Gt[1024];                    // GELU LUT
  __shared__ float2 Red[64 * 8];                 // LN2 partials [row][slot]
  const int t = threadIdx.x;
  const int row0 = blockIdx.x * 64;
  stage128(pwb, 128, Wt);                        // async
  stage64(A + (size_t)row0 * 128, Ht);           // async
  #pragma unroll
  for (int i = t; i < 1024; i += 256) {
    const float x0 = (float)i * 0.0078125f - 4.f;
    const float g0 = gelu_f(x0);
    Gt[i] = make_float2(g0, gelu_f(x0 + 0.0078125f) - g0);
  }
  const int l = t & 63, w = t >> 6, w0 = w & 1, w1 = w >> 1;
  const int g = l >> 4, rl = l & 15;
  // early scattered x loads + output offsets for this thread's 2 rows
  size_t obase[2];
  float4 xv[4][2];
  #pragma unroll
  for (int j = 0; j < 2; ++j) {
    const int r = row0 + w1 * 32 + j * 16 + rl;
    const int wn = r >> 6, n = r & 63;
    const int b_ = wn >> 10, rem = wn & 1023;
    const int wh = rem >> 5, ww = rem & 31;
    const int si = n >> 3, sj = n & 7;
    const int hd = (wh * 8 + si + 4) & 255;
    const int wd = (ww * 8 + sj + 4) & 255;
    obase[j] = (((size_t)b_ << 16) + hd * 256 + wd) * 128;
    #pragma unroll
    for (int i = 0; i < 4; ++i)
      xv[i][j] = *(const float4*)(xin + obase[j] + w0 * 64 + i * 16 + 4 * g);
  }
  __syncthreads();                               // Wt (projW) + Ht (attn) staged
  const f32x4 z = {0.f, 0.f, 0.f, 0.f};
  // ---- proj MFMA (same shape as fc2) ----
  f32x4 x2r[4][2];
  #pragma unroll
  for (int i = 0; i < 4; ++i) { x2r[i][0] = z; x2r[i][1] = z; }
  #pragma unroll
  for (int kk = 0; kk < 4; ++kk) {
    short8v a[4], b[2];
    #pragma unroll
    for (int i = 0; i < 4; ++i) a[i] = frag_ld(Wt, w0 * 64 + i * 16 + rl, kk * 4 + g);
    #pragma unroll
    for (int j = 0; j < 2; ++j) b[j] = frag_ld(Ht, w1 * 32 + j * 16 + rl, kk * 4 + g);
    #pragma unroll
    for (int i = 0; i < 4; ++i)
      #pragma unroll
      for (int j = 0; j < 2; ++j)
        x2r[i][j] = mfma32(a[i], b[j], x2r[i][j]);
  }
  // x2 = proj + pb + x (registers only); LN2 partials
  #pragma unroll
  for (int i = 0; i < 4; ++i) {
    const float4 bv = *(const float4*)(pb + w0 * 64 + i * 16 + 4 * g);
    #pragma unroll
    for (int j = 0; j < 2; ++j) {
      x2r[i][j][0] += xv[i][j].x + bv.x;
      x2r[i][j][1] += xv[i][j].y + bv.y;
      x2r[i][j][2] += xv[i][j].z + bv.z;
      x2r[i][j][3] += xv[i][j].w + bv.w;
    }
  }
  #pragma unroll
  for (int j = 0; j < 2; ++j) {
    float s = 0.f, ss = 0.f;
    #pragma unroll
    for (int i = 0; i < 4; ++i)
      #pragma unroll
      for (int e = 0; e < 4; ++e) { const float v = x2r[i][j][e]; s += v; ss += v * v; }
    Red[(w1 * 32 + j * 16 + rl) * 8 + (w0 * 4 + g)] = make_float2(s, ss);
  }
  __syncthreads();
  float mean[2], rstd[2];
  #pragma unroll
  for (int j = 0; j < 2; ++j) {
    const float2* rp = &Red[(w1 * 32 + j * 16 + rl) * 8];
    float s = 0.f, ss = 0.f;
    #pragma unroll
    for (int k = 0; k < 8; ++k) { s += rp[k].x; ss += rp[k].y; }
    mean[j] = s * 0.0078125f;
    rstd[j] = rsqrtf(ss * 0.0078125f - mean[j] * mean[j] + LNEPS);
  }
  // write ln2(x2) -> Xt
  #pragma unroll
  for (int i = 0; i < 4; ++i) {
    const int c = w0 * 64 + i * 16 + 4 * g;
    const float4 g4 = *(const float4*)(gw + c);
    const float4 c4 = *(const float4*)(gb + c);
    #pragma unroll
    for (int j = 0; j < 2; ++j) {
      const int r = w1 * 32 + j * 16 + rl;
      ushort4 p;
      p.x = f2bf((x2r[i][j][0] - mean[j]) * rstd[j] * g4.x + c4.x);
      p.y = f2bf((x2r[i][j][1] - mean[j]) * rstd[j] * g4.y + c4.y);
      p.z = f2bf((x2r[i][j][2] - mean[j]) * rstd[j] * g4.z + c4.z);
      p.w = f2bf((x2r[i][j][3] - mean[j]) * rstd[j] * g4.w + c4.w);
      const int chunk = c >> 3, inner = (c & 7) * 2;
      *(ushort4*)((char*)Xt + r * 256 + ((chunk ^ (r & 7)) << 4) + inner) = p;
    }
  }
  // ---- MLP main loop (r10 k5 structure) ----
  f32x4 oacc[4][2];
  #pragma unroll
  for (int i = 0; i < 4; ++i) { oacc[i][0] = z; oacc[i][1] = z; }
  for (int sb = 0; sb < 4; ++sb) {
    __syncthreads();
    stage128(w1b + (size_t)sb * 128 * 128, 128, Wt);
    __syncthreads();
    f32x4 hacc[4][2];
    #pragma unroll
    for (int i = 0; i < 4; ++i) { hacc[i][0] = z; hacc[i][1] = z; }
    #pragma unroll
    for (int kk = 0; kk < 4; ++kk) {
      short8v a[4], b[2];
      #pragma unroll
      for (int i = 0; i < 4; ++i) a[i] = frag_ld(Wt, w0 * 64 + i * 16 + rl, kk * 4 + g);
      #pragma unroll
      for (int j = 0; j < 2; ++j) b[j] = frag_ld(Xt, w1 * 32 + j * 16 + rl, kk * 4 + g);
      #pragma unroll
      for (int i = 0; i < 4; ++i)
        #pragma unroll
        for (int j = 0; j < 2; ++j)
          hacc[i][j] = mfma32(a[i], b[j], hacc[i][j]);
    }
    __syncthreads();
    #pragma unroll
    for (int i = 0; i < 4; ++i) {
      const int cl = w0 * 64 + i * 16 + 4 * g;
      const float4 b1v = *(const float4*)(b1 + sb * 128 + cl);
      const float ba[4] = {b1v.x, b1v.y, b1v.z, b1v.w};
      #pragma unroll
      for (int j = 0; j < 2; ++j) {
        const int r = w1 * 32 + j * 16 + rl;
        unsigned short pe[4];
        #pragma unroll
        for (int e = 0; e < 4; ++e) {
          const float xh = hacc[i][j][e] + ba[e];
          float tq = fmaf(xh, 128.f, 512.f);
          tq = fminf(fmaxf(tq, 0.f), 1023.99f);
          const float fi = floorf(tq);
          const float2 ent = Gt[(int)fi];
          float gv = fmaf(tq - fi, ent.y, ent.x);
          gv = xh > 3.98f ? xh : gv;
          pe[e] = f2bf(gv);
        }
        ushort4 p = { pe[0], pe[1], pe[2], pe[3] };
        const int chunk = cl >> 3, inner = (cl & 7) * 2;
        *(ushort4*)((char*)Ht + r * 256 + ((chunk ^ (r & 7)) << 4) + inner) = p;
      }
    }
    stage128(w2b + (size_t)sb * 128, 512, Wt);
    __syncthreads();
    #pragma unroll
    for (int kk = 0; kk < 4; ++kk) {
      short8v a[4], b[2];
      #pragma unroll
      for (int i = 0; i < 4; ++i) a[i] = frag_ld(Wt, w0 * 64 + i * 16 + rl, kk * 4 + g);
      #pragma unroll
      for (int j = 0; j < 2; ++j) b[j] = frag_ld(Ht, w1 * 32 + j * 16 + rl, kk * 4 + g);
      #pragma unroll
      for (int i = 0; i < 4; ++i)
        #pragma unroll
        for (int j = 0; j < 2; ++j)
          oacc[i][j] = mfma32(a[i], b[j], oacc[i][j]);
    }
  }
  // ---- epilogue: out = x2(reg) + oacc + b2 at scattered positions ----
  #pragma unroll
  for (int i = 0; i < 4; ++i) {
    const int c = w0 * 64 + i * 16 + 4 * g;
    const float4 bv = *(const float4*)(b2 + c);
    #pragma unroll
    for (int j = 0; j < 2; ++j) {
      float4 o = { x2r[i][j][0] + oacc[i][j][0] + bv.x,
                   x2r[i][j][1] + oacc[i][j][1] + bv.y,
                   x2r[i][j][2] + oacc[i][j][2] + bv.z,
                   x2r[i][j][3] + oacc[i][j][3] + bv.w };
      *(float4*)(out + obase[j] + c) = o;
    }
  }
}

extern "C" void kernel_launch(void* const* d_in, const int* in_sizes, int n_in,
                              void* d_out, int out_size, void* d_ws, size_t ws_size,
                              hipStream_t stream)
{
  const float* x    = (const float*)d_in[0];
  const float* n1w  = (const float*)d_in[1];
  const float* n1b  = (const float*)d_in[2];
  const float* qkvw = (const float*)d_in[3];
  const float* qkvB = (const float*)d_in[4];
  const float* relb = (const float*)d_in[5];
  const float* pw   = (const float*)d_in[6];
  const float* pb   = (const float*)d_in[7];
  const float* n2w  = (const float*)d_in[8];
  const float* n2b  = (const float*)d_in[9];
  const float* w1   = (const float*)d_in[10];
  const float* b1   = (const float*)d_in[11];
  const float* w2   = (const float*)d_in[12];
  const float* b2   = (const float*)d_in[13];
  float* out = (float*)d_out;

  unsigned short* winb = (unsigned short*)d_ws;        // 16,777,216 el  attn out
  unsigned short* qkb  = winb + 16777216;              // 33,554,432 el  Q|K interleaved [row][256]
  unsigned short* vtb  = qkb + 33554432;               // 16,777,216 el  V^T per (win,head): [16][64]
  unsigned short* wb   = vtb + 16777216;               // 196,608 el  bf16 weights
  unsigned short* qkvw_b = wb;
  unsigned short* pw_b   = wb + 49152;
  unsigned short* w1_b   = wb + 65536;
  unsigned short* w2_b   = wb + 131072;

  k0_cvt<<<192, 256, 0, stream>>>(qkvw, pw, w1, w2, wb);
  k2_qkv<<<1024, 256, 0, stream>>>(x, n1w, n1b, qkvw_b, qkvB, qkb, vtb);
  k3_attn<<<4096, 256, 0, stream>>>(qkb, vtb, relb, winb);
  k45_proj_mlp<<<2048, 256, 0, stream>>>(winb, pw_b, pb, x, n2w, n2b,
                                         w1_b, b1, w2_b, b2, out);
}

// Round 12
// 177.195 us; speedup vs baseline: 2.0171x; 1.0288x over previous
//
#include <hip/hip_runtime.h>
#include <hip/hip_bf16.h>
#include <cmath>

#define LNEPS 1e-5f

typedef __attribute__((ext_vector_type(8))) short short8v;
typedef __attribute__((ext_vector_type(4))) float f32x4;

__device__ __forceinline__ unsigned short f2bf(float f){
  unsigned u = __float_as_uint(f);
  u += 0x7fffu + ((u >> 16) & 1u);
  return (unsigned short)(u >> 16);
}
__device__ __forceinline__ float gelu_f(float x){
  return 0.5f * x * (1.f + erff(x * 0.70710678118654752f));   // exact; used for LUT build
}

__device__ __forceinline__ f32x4 mfma32(short8v a, short8v b, f32x4 c){
#ifdef __HIP_DEVICE_COMPILE__
  return __builtin_amdgcn_mfma_f32_16x16x32_bf16(a, b, c, 0, 0, 0);
#else
  return c;
#endif
}

// Stage 128x128 bf16 -> LDS via global_load_lds, 256 threads (8 iters).
__device__ __forceinline__ void stage128(const unsigned short* g, int ldg, short* lds){
#ifdef __HIP_DEVICE_COMPILE__
  const int t = threadIdx.x;
  const int wv = t >> 6;
  #pragma unroll
  for (int it = 0; it < 8; ++it) {
    const int flat = it * 256 + t;
    const int r = flat >> 4, c = flat & 15;
    const unsigned short* src = g + (size_t)r * ldg + ((c ^ (r & 7)) << 3);
    short* dst = lds + (size_t)(it * 256 + wv * 64) * 8;
    __builtin_amdgcn_global_load_lds(
        (const __attribute__((address_space(1))) void*)src,
        (__attribute__((address_space(3))) void*)dst, 16, 0, 0);
  }
#else
  (void)g; (void)ldg; (void)lds;
#endif
}
// Same, for 512-thread blocks (4 iters).
__device__ __forceinline__ void stage128_512(const unsigned short* g, int ldg, short* lds){
#ifdef __HIP_DEVICE_COMPILE__
  const int t = threadIdx.x;
  const int wv = t >> 6;
  #pragma unroll
  for (int it = 0; it < 4; ++it) {
    const int flat = it * 512 + t;
    const int r = flat >> 4, c = flat & 15;
    const unsigned short* src = g + (size_t)r * ldg + ((c ^ (r & 7)) << 3);
    short* dst = lds + (size_t)(it * 512 + wv * 64) * 8;
    __builtin_amdgcn_global_load_lds(
        (const __attribute__((address_space(1))) void*)src,
        (__attribute__((address_space(3))) void*)dst, 16, 0, 0);
  }
#else
  (void)g; (void)ldg; (void)lds;
#endif
}
// Stage 64x128 bf16 (256 threads).
__device__ __forceinline__ void stage64(const unsigned short* g, short* lds){
#ifdef __HIP_DEVICE_COMPILE__
  const int t = threadIdx.x;
  const int wv = t >> 6;
  #pragma unroll
  for (int it = 0; it < 4; ++it) {
    const int flat = it * 256 + t;
    const int r = flat >> 4, c = flat & 15;
    const unsigned short* src = g + (size_t)r * 128 + ((c ^ (r & 7)) << 3);
    short* dst = lds + (size_t)(it * 256 + wv * 64) * 8;
    __builtin_amdgcn_global_load_lds(
        (const __attribute__((address_space(1))) void*)src,
        (__attribute__((address_space(3))) void*)dst, 16, 0, 0);
  }
#else
  (void)g; (void)lds;
#endif
}
// Swizzled 16B fragment read: row-major [row][128 bf16] (256B rows).
__device__ __forceinline__ short8v frag_ld(const short* lds, int row, int chunk){
  return *(const short8v*)((const char*)lds + row * 256 + ((chunk ^ (row & 7)) << 4));
}

// ---------------- K0: weights f32 -> bf16 ----------------
__global__ __launch_bounds__(256) void k0_cvt(
    const float* __restrict__ qkvw, const float* __restrict__ pw,
    const float* __restrict__ w1, const float* __restrict__ w2,
    unsigned short* __restrict__ dst)
{
  const int i = (blockIdx.x * 256 + threadIdx.x) * 4;
  const float* src; int off;
  if (i < 49152)       { src = qkvw; off = i; }
  else if (i < 65536)  { src = pw;   off = i - 49152; }
  else if (i < 131072) { src = w1;   off = i - 65536; }
  else                 { src = w2;   off = i - 131072; }
  const float4 v = *(const float4*)(src + off);
  ushort4 o = { f2bf(v.x), f2bf(v.y), f2bf(v.z), f2bf(v.w) };
  *(ushort4*)(dst + i) = o;
}

// ---------------- K23: fused LN1+shift+window + qkv GEMM + window attention ----------------
// 512 threads, block owns 128 window-rows = 2 complete windows. Q|K/V^T/P all in LDS.
__global__ __launch_bounds__(512, 2) void k23_qkv_attn(
    const float* __restrict__ x,
    const float* __restrict__ gw, const float* __restrict__ gb,
    const unsigned short* __restrict__ Wb,
    const float* __restrict__ bias,
    const float* __restrict__ table,
    unsigned short* __restrict__ attn)
{
  __shared__ __align__(16) short At[128 * 128];    // 32 KB: weight tile; later P (4 KB/wave)
  __shared__ __align__(16) short Bt[128 * 128];    // 32 KB: ln1(x); later V^T [2][8][16][64]
  __shared__ __align__(16) short QKl[128 * 256];   // 64 KB: Q|K per row (512B rows, swizzled)
  __shared__ float Tb[1800];                       // 7.2 KB: rel-bias table
  const int t = threadIdx.x;
  const int row0 = blockIdx.x * 128;
  stage128_512(Wb, 128, At);                       // Wq tile, async under LN
  for (int i = t; i < 1800; i += 512) Tb[i] = table[i];
  // ---- LN1 + shift + window partition -> Bt (16 threads/row) ----
  #pragma unroll
  for (int it = 0; it < 4; ++it) {
    const int flat = it * 512 + t;
    const int r = flat >> 4, c = flat & 15;
    const int row = row0 + r;
    const int wid = row >> 6, n = row & 63;
    const int b = wid >> 10, rem = wid & 1023;
    const int wh = rem >> 5, wwi = rem & 31;
    const int i2 = n >> 3, j2 = n & 7;
    const int sh = (wh * 8 + i2 + 4) & 255;
    const int sw = (wwi * 8 + j2 + 4) & 255;
    const float* src = x + (((size_t)b << 16) + sh * 256 + sw) * 128 + c * 8;
    const float4 a0 = *(const float4*)src;
    const float4 a1 = *(const float4*)(src + 4);
    float s  = a0.x + a0.y + a0.z + a0.w + a1.x + a1.y + a1.z + a1.w;
    float ss = a0.x*a0.x + a0.y*a0.y + a0.z*a0.z + a0.w*a0.w
             + a1.x*a1.x + a1.y*a1.y + a1.z*a1.z + a1.w*a1.w;
    s += __shfl_xor(s, 1); ss += __shfl_xor(ss, 1);
    s += __shfl_xor(s, 2); ss += __shfl_xor(ss, 2);
    s += __shfl_xor(s, 4); ss += __shfl_xor(ss, 4);
    s += __shfl_xor(s, 8); ss += __shfl_xor(ss, 8);
    const float mean = s * 0.0078125f;
    const float rstd = rsqrtf(ss * 0.0078125f - mean * mean + LNEPS);
    const float4 g0 = *(const float4*)(gw + c * 8), g1 = *(const float4*)(gw + c * 8 + 4);
    const float4 c0 = *(const float4*)(gb + c * 8), c1 = *(const float4*)(gb + c * 8 + 4);
    uint4 pk;
    pk.x = (unsigned)f2bf((a0.x - mean) * rstd * g0.x + c0.x)
         | ((unsigned)f2bf((a0.y - mean) * rstd * g0.y + c0.y) << 16);
    pk.y = (unsigned)f2bf((a0.z - mean) * rstd * g0.z + c0.z)
         | ((unsigned)f2bf((a0.w - mean) * rstd * g0.w + c0.w) << 16);
    pk.z = (unsigned)f2bf((a1.x - mean) * rstd * g1.x + c1.x)
         | ((unsigned)f2bf((a1.y - mean) * rstd * g1.y + c1.y) << 16);
    pk.w = (unsigned)f2bf((a1.z - mean) * rstd * g1.z + c1.z)
         | ((unsigned)f2bf((a1.w - mean) * rstd * g1.w + c1.w) << 16);
    *(uint4*)((char*)Bt + r * 256 + ((c ^ (r & 7)) << 4)) = pk;
  }
  __syncthreads();                                 // Bt + Wq + Tb ready

  const int l = t & 63, w = t >> 6, w0 = w & 1, w1 = w >> 1;   // w1 in 0..3
  const int g = l >> 4, rl = l & 15;
  const f32x4 z = {0.f, 0.f, 0.f, 0.f};

  // ---- qkv GEMM: 3 weight tiles; Q|K -> QKl, V -> VtL (Bt space) ----
  for (int nt = 0; nt < 3; ++nt) {
    f32x4 acc[4][2];
    #pragma unroll
    for (int i = 0; i < 4; ++i) { acc[i][0] = z; acc[i][1] = z; }
    #pragma unroll
    for (int kk = 0; kk < 4; ++kk) {
      short8v a[4], b[2];
      #pragma unroll
      for (int i = 0; i < 4; ++i) a[i] = frag_ld(At, w0 * 64 + i * 16 + rl, kk * 4 + g);
      #pragma unroll
      for (int j = 0; j < 2; ++j) b[j] = frag_ld(Bt, w1 * 32 + j * 16 + rl, kk * 4 + g);
      #pragma unroll
      for (int i = 0; i < 4; ++i)
        #pragma unroll
        for (int j = 0; j < 2; ++j)
          acc[i][j] = mfma32(a[i], b[j], acc[i][j]);
    }
    if (nt < 2) {
      #pragma unroll
      for (int i = 0; i < 4; ++i) {
        const int c = w0 * 64 + i * 16 + 4 * g;
        const float4 bv = *(const float4*)(bias + nt * 128 + c);
        const int chunk = nt * 16 + (c >> 3), inner = (c & 7) * 2;
        #pragma unroll
        for (int j = 0; j < 2; ++j) {
          const int r = w1 * 32 + j * 16 + rl;
          ushort4 o = { f2bf(acc[i][j][0] + bv.x), f2bf(acc[i][j][1] + bv.y),
                        f2bf(acc[i][j][2] + bv.z), f2bf(acc[i][j][3] + bv.w) };
          *(ushort4*)((char*)QKl + r * 512 + ((chunk ^ (r & 7)) << 4) + inner) = o;
        }
      }
      __syncthreads();                             // At reads done
      stage128_512(Wb + (size_t)(nt + 1) * 16384, 128, At);
      __syncthreads();                             // next weight tile ready
    } else {
      __syncthreads();                             // all At/Bt reads done -> Bt reusable
      #pragma unroll
      for (int i = 0; i < 4; ++i) {
        const int c = w0 * 64 + i * 16 + 4 * g;
        const int h2 = c >> 4, db = c & 15;        // h2 = w0*4+i, db = 4g
        const float4 bv = *(const float4*)(bias + 256 + c);
        const float ba[4] = {bv.x, bv.y, bv.z, bv.w};
        #pragma unroll
        for (int j = 0; j < 2; ++j) {
          const int r = w1 * 32 + j * 16 + rl;
          const int wl = r >> 6, m = r & 63;
          char* vb = (char*)Bt + (wl * 8 + h2) * 2048;
          #pragma unroll
          for (int e = 0; e < 4; ++e) {
            const int d = db + e;
            *(unsigned short*)(vb + d * 128 + (((m >> 3) ^ (d & 7)) << 4) + (m & 7) * 2)
                = f2bf(acc[i][j][e] + ba[e]);
          }
        }
      }
      __syncthreads();                             // VtL visible
    }
  }

  // ---- attention: wave w handles head w of both windows ----
  const int h = w;
  char* Pw = (char*)At + w * 4096;                 // per-wave P half [64 r][32 m] bf16
  const short8v zz = {0,0,0,0,0,0,0,0};
  for (int wl = 0; wl < 2; ++wl) {
    const int win = blockIdx.x * 2 + wl;
    short8v qf[4], kf[4];
    if (g < 2) {
      #pragma unroll
      for (int rf = 0; rf < 4; ++rf) {
        const int r = wl * 64 + rf * 16 + rl;
        qf[rf] = *(const short8v*)((char*)QKl + r * 512 + (((2 * h + g) ^ (r & 7)) << 4));
      }
      #pragma unroll
      for (int mf = 0; mf < 4; ++mf) {
        const int r = wl * 64 + mf * 16 + rl;
        kf[mf] = *(const short8v*)((char*)QKl + r * 512 + (((16 + 2 * h + g) ^ (r & 7)) << 4));
      }
    } else {
      #pragma unroll
      for (int i = 0; i < 4; ++i) { qf[i] = zz; kf[i] = zz; }
    }
    f32x4 s[4][4];
    #pragma unroll
    for (int mf = 0; mf < 4; ++mf)
      #pragma unroll
      for (int rf = 0; rf < 4; ++rf)
        s[mf][rf] = mfma32(kf[mf], qf[rf], z);     // S^T: m = mf*16+4g+e, r = rf*16+rl
    float sum[4];
    #pragma unroll
    for (int rf = 0; rf < 4; ++rf) {
      const int r = rf * 16 + rl, i1 = r >> 3, j1 = r & 7;
      float mx = -1e30f;
      #pragma unroll
      for (int mf = 0; mf < 4; ++mf)
        #pragma unroll
        for (int e = 0; e < 4; ++e) {
          const int m = mf * 16 + g * 4 + e;
          const int i2 = m >> 3, j2 = m & 7;
          const float v = s[mf][rf][e] * 0.25f + Tb[((i1 - i2 + 7) * 15 + (j1 - j2 + 7)) * 8 + h];
          s[mf][rf][e] = v;
          mx = fmaxf(mx, v);
        }
      mx = fmaxf(mx, __shfl_xor(mx, 16));
      mx = fmaxf(mx, __shfl_xor(mx, 32));
      float sm = 0.f;
      #pragma unroll
      for (int mf = 0; mf < 4; ++mf)
        #pragma unroll
        for (int e = 0; e < 4; ++e) {
          const float ev = __expf(s[mf][rf][e] - mx);
          s[mf][rf][e] = ev;
          sm += ev;
        }
      sm += __shfl_xor(sm, 16);
      sm += __shfl_xor(sm, 32);
      sum[rf] = sm;
    }
    // PV in two m-halves through the per-wave P buffer (intra-wave ordering).
    const char* vbase = (char*)Bt + (wl * 8 + h) * 2048;
    f32x4 o[4];
    #pragma unroll
    for (int rf = 0; rf < 4; ++rf) o[rf] = z;
    #pragma unroll
    for (int hm = 0; hm < 2; ++hm) {
      #pragma unroll
      for (int rf = 0; rf < 4; ++rf) {
        const int r = rf * 16 + rl;
        #pragma unroll
        for (int mfl = 0; mfl < 2; ++mfl) {
          const int mf = hm * 2 + mfl;
          uint2 u;
          u.x = (unsigned)f2bf(s[mf][rf][0]) | ((unsigned)f2bf(s[mf][rf][1]) << 16);
          u.y = (unsigned)f2bf(s[mf][rf][2]) | ((unsigned)f2bf(s[mf][rf][3]) << 16);
          *(uint2*)(Pw + r * 64 + (((mfl * 2 + (g >> 1)) ^ ((r >> 1) & 3)) << 4) + (g & 1) * 8) = u;
        }
      }
      const short8v va = *(const short8v*)(vbase + rl * 128 + (((hm * 4 + g) ^ (rl & 7)) << 4));
      #pragma unroll
      for (int rf = 0; rf < 4; ++rf) {
        const int r = rf * 16 + rl;
        const short8v pb = *(const short8v*)(Pw + r * 64 + ((g ^ ((r >> 1) & 3)) << 4));
        o[rf] = mfma32(va, pb, o[rf]);
      }
    }
    #pragma unroll
    for (int rf = 0; rf < 4; ++rf) {
      const float inv = 1.f / sum[rf];
      const int r = rf * 16 + rl;
      ushort4 ov = { f2bf(o[rf][0] * inv), f2bf(o[rf][1] * inv),
                     f2bf(o[rf][2] * inv), f2bf(o[rf][3] * inv) };
      *(ushort4*)(attn + ((size_t)win * 64 + r) * 128 + h * 16 + g * 4) = ov;
    }
  }
}

// ---------------- K45: fused proj + unshift-residual + LN2 + fc1 + GELU + fc2 + residual ----------------
__global__ __launch_bounds__(256, 2) void k45_proj_mlp(
    const unsigned short* __restrict__ A,
    const unsigned short* __restrict__ pwb,
    const float* __restrict__ pb,
    const float* __restrict__ xin,
    const float* __restrict__ gw, const float* __restrict__ gb,
    const unsigned short* __restrict__ w1b, const float* __restrict__ b1,
    const unsigned short* __restrict__ w2b, const float* __restrict__ b2,
    float* __restrict__ out)
{
  __shared__ __align__(16) short Xt[64 * 128];
  __shared__ __align__(16) short Ht[64 * 128];
  __shared__ __align__(16) short Wt[128 * 128];
  __shared__ float2 Gt[1024];
  __shared__ float2 Red[64 * 8];
  const int t = threadIdx.x;
  const int row0 = blockIdx.x * 64;
  stage128(pwb, 128, Wt);
  stage64(A + (size_t)row0 * 128, Ht);
  #pragma unroll
  for (int i = t; i < 1024; i += 256) {
    const float x0 = (float)i * 0.0078125f - 4.f;
    const float g0 = gelu_f(x0);
    Gt[i] = make_float2(g0, gelu_f(x0 + 0.0078125f) - g0);
  }
  const int l = t & 63, w = t >> 6, w0 = w & 1, w1 = w >> 1;
  const int g = l >> 4, rl = l & 15;
  size_t obase[2];
  float4 xv[4][2];
  #pragma unroll
  for (int j = 0; j < 2; ++j) {
    const int r = row0 + w1 * 32 + j * 16 + rl;
    const int wn = r >> 6, n = r & 63;
    const int b_ = wn >> 10, rem = wn & 1023;
    const int wh = rem >> 5, ww = rem & 31;
    const int si = n >> 3, sj = n & 7;
    const int hd = (wh * 8 + si + 4) & 255;
    const int wd = (ww * 8 + sj + 4) & 255;
    obase[j] = (((size_t)b_ << 16) + hd * 256 + wd) * 128;
    #pragma unroll
    for (int i = 0; i < 4; ++i)
      xv[i][j] = *(const float4*)(xin + obase[j] + w0 * 64 + i * 16 + 4 * g);
  }
  __syncthreads();
  const f32x4 z = {0.f, 0.f, 0.f, 0.f};
  f32x4 x2r[4][2];
  #pragma unroll
  for (int i = 0; i < 4; ++i) { x2r[i][0] = z; x2r[i][1] = z; }
  #pragma unroll
  for (int kk = 0; kk < 4; ++kk) {
    short8v a[4], b[2];
    #pragma unroll
    for (int i = 0; i < 4; ++i) a[i] = frag_ld(Wt, w0 * 64 + i * 16 + rl, kk * 4 + g);
    #pragma unroll
    for (int j = 0; j < 2; ++j) b[j] = frag_ld(Ht, w1 * 32 + j * 16 + rl, kk * 4 + g);
    #pragma unroll
    for (int i = 0; i < 4; ++i)
      #pragma unroll
      for (int j = 0; j < 2; ++j)
        x2r[i][j] = mfma32(a[i], b[j], x2r[i][j]);
  }
  #pragma unroll
  for (int i = 0; i < 4; ++i) {
    const float4 bv = *(const float4*)(pb + w0 * 64 + i * 16 + 4 * g);
    #pragma unroll
    for (int j = 0; j < 2; ++j) {
      x2r[i][j][0] += xv[i][j].x + bv.x;
      x2r[i][j][1] += xv[i][j].y + bv.y;
      x2r[i][j][2] += xv[i][j].z + bv.z;
      x2r[i][j][3] += xv[i][j].w + bv.w;
    }
  }
  #pragma unroll
  for (int j = 0; j < 2; ++j) {
    float s = 0.f, ss = 0.f;
    #pragma unroll
    for (int i = 0; i < 4; ++i)
      #pragma unroll
      for (int e = 0; e < 4; ++e) { const float v = x2r[i][j][e]; s += v; ss += v * v; }
    Red[(w1 * 32 + j * 16 + rl) * 8 + (w0 * 4 + g)] = make_float2(s, ss);
  }
  __syncthreads();
  float mean[2], rstd[2];
  #pragma unroll
  for (int j = 0; j < 2; ++j) {
    const float2* rp = &Red[(w1 * 32 + j * 16 + rl) * 8];
    float s = 0.f, ss = 0.f;
    #pragma unroll
    for (int k = 0; k < 8; ++k) { s += rp[k].x; ss += rp[k].y; }
    mean[j] = s * 0.0078125f;
    rstd[j] = rsqrtf(ss * 0.0078125f - mean[j] * mean[j] + LNEPS);
  }
  #pragma unroll
  for (int i = 0; i < 4; ++i) {
    const int c = w0 * 64 + i * 16 + 4 * g;
    const float4 g4 = *(const float4*)(gw + c);
    const float4 c4 = *(const float4*)(gb + c);
    #pragma unroll
    for (int j = 0; j < 2; ++j) {
      const int r = w1 * 32 + j * 16 + rl;
      ushort4 p;
      p.x = f2bf((x2r[i][j][0] - mean[j]) * rstd[j] * g4.x + c4.x);
      p.y = f2bf((x2r[i][j][1] - mean[j]) * rstd[j] * g4.y + c4.y);
      p.z = f2bf((x2r[i][j][2] - mean[j]) * rstd[j] * g4.z + c4.z);
      p.w = f2bf((x2r[i][j][3] - mean[j]) * rstd[j] * g4.w + c4.w);
      const int chunk = c >> 3, inner = (c & 7) * 2;
      *(ushort4*)((char*)Xt + r * 256 + ((chunk ^ (r & 7)) << 4) + inner) = p;
    }
  }
  f32x4 oacc[4][2];
  #pragma unroll
  for (int i = 0; i < 4; ++i) { oacc[i][0] = z; oacc[i][1] = z; }
  for (int sb = 0; sb < 4; ++sb) {
    __syncthreads();
    stage128(w1b + (size_t)sb * 128 * 128, 128, Wt);
    __syncthreads();
    f32x4 hacc[4][2];
    #pragma unroll
    for (int i = 0; i < 4; ++i) { hacc[i][0] = z; hacc[i][1] = z; }
    #pragma unroll
    for (int kk = 0; kk < 4; ++kk) {
      short8v a[4], b[2];
      #pragma unroll
      for (int i = 0; i < 4; ++i) a[i] = frag_ld(Wt, w0 * 64 + i * 16 + rl, kk * 4 + g);
      #pragma unroll
      for (int j = 0; j < 2; ++j) b[j] = frag_ld(Xt, w1 * 32 + j * 16 + rl, kk * 4 + g);
      #pragma unroll
      for (int i = 0; i < 4; ++i)
        #pragma unroll
        for (int j = 0; j < 2; ++j)
          hacc[i][j] = mfma32(a[i], b[j], hacc[i][j]);
    }
    __syncthreads();
    #pragma unroll
    for (int i = 0; i < 4; ++i) {
      const int cl = w0 * 64 + i * 16 + 4 * g;
      const float4 b1v = *(const float4*)(b1 + sb * 128 + cl);
      const float ba[4] = {b1v.x, b1v.y, b1v.z, b1v.w};
      #pragma unroll
      for (int j = 0; j < 2; ++j) {
        const int r = w1 * 32 + j * 16 + rl;
        unsigned short pe[4];
        #pragma unroll
        for (int e = 0; e < 4; ++e) {
          const float xh = hacc[i][j][e] + ba[e];
          float tq = fmaf(xh, 128.f, 512.f);
          tq = fminf(fmaxf(tq, 0.f), 1023.99f);
          const float fi = floorf(tq);
          const float2 ent = Gt[(int)fi];
          float gv = fmaf(tq - fi, ent.y, ent.x);
          gv = xh > 3.98f ? xh : gv;
          pe[e] = f2bf(gv);
        }
        ushort4 p = { pe[0], pe[1], pe[2], pe[3] };
        const int chunk = cl >> 3, inner = (cl & 7) * 2;
        *(ushort4*)((char*)Ht + r * 256 + ((chunk ^ (r & 7)) << 4) + inner) = p;
      }
    }
    stage128(w2b + (size_t)sb * 128, 512, Wt);
    __syncthreads();
    #pragma unroll
    for (int kk = 0; kk < 4; ++kk) {
      short8v a[4], b[2];
      #pragma unroll
      for (int i = 0; i < 4; ++i) a[i] = frag_ld(Wt, w0 * 64 + i * 16 + rl, kk * 4 + g);
      #pragma unroll
      for (int j = 0; j < 2; ++j) b[j] = frag_ld(Ht, w1 * 32 + j * 16 + rl, kk * 4 + g);
      #pragma unroll
      for (int i = 0; i < 4; ++i)
        #pragma unroll
        for (int j = 0; j < 2; ++j)
          oacc[i][j] = mfma32(a[i], b[j], oacc[i][j]);
    }
  }
  #pragma unroll
  for (int i = 0; i < 4; ++i) {
    const int c = w0 * 64 + i * 16 + 4 * g;
    const float4 bv = *(const float4*)(b2 + c);
    #pragma unroll
    for (int j = 0; j < 2; ++j) {
      float4 o = { x2r[i][j][0] + oacc[i][j][0] + bv.x,
                   x2r[i][j][1] + oacc[i][j][1] + bv.y,
                   x2r[i][j][2] + oacc[i][j][2] + bv.z,
                   x2r[i][j][3] + oacc[i][j][3] + bv.w };
      *(float4*)(out + obase[j] + c) = o;
    }
  }
}

extern "C" void kernel_launch(void* const* d_in, const int* in_sizes, int n_in,
                              void* d_out, int out_size, void* d_ws, size_t ws_size,
                              hipStream_t stream)
{
  const float* x    = (const float*)d_in[0];
  const float* n1w  = (const float*)d_in[1];
  const float* n1b  = (const float*)d_in[2];
  const float* qkvw = (const float*)d_in[3];
  const float* qkvB = (const float*)d_in[4];
  const float* relb = (const float*)d_in[5];
  const float* pw   = (const float*)d_in[6];
  const float* pb   = (const float*)d_in[7];
  const float* n2w  = (const float*)d_in[8];
  const float* n2b  = (const float*)d_in[9];
  const float* w1   = (const float*)d_in[10];
  const float* b1   = (const float*)d_in[11];
  const float* w2   = (const float*)d_in[12];
  const float* b2   = (const float*)d_in[13];
  float* out = (float*)d_out;

  unsigned short* winb = (unsigned short*)d_ws;        // attn out [131072][128] bf16
  unsigned short* wb   = winb + 16777216;              // bf16 weights
  unsigned short* qkvw_b = wb;
  unsigned short* pw_b   = wb + 49152;
  unsigned short* w1_b   = wb + 65536;
  unsigned short* w2_b   = wb + 131072;

  k0_cvt<<<192, 256, 0, stream>>>(qkvw, pw, w1, w2, wb);
  k23_qkv_attn<<<1024, 512, 0, stream>>>(x, n1w, n1b, qkvw_b, qkvB, relb, winb);
  k45_proj_mlp<<<2048, 256, 0, stream>>>(winb, pw_b, pb, x, n2w, n2b,
                                         w1_b, b1, w2_b, b2, out);
}